// Round 17
// baseline (1235.483 us; speedup 1.0000x reference)
//
#include <hip/hip_runtime.h>
#include <hip/hip_bf16.h>
#include <cstdio>

#define Bz 2
#define Sz 4096
#define Dz 1024
#define DIz 2048
#define DSz 16
#define DTRz 64
#define NE 8
#define Fz 1024
#define FSz 2048
#define Tz (Bz*Sz)            // 8192 tokens
#define NDH 1024              // d-half width
#define NCH2 64
#define CL2 (Sz/NCH2)         // 64
#define SLOTCAP 17408         // 136 tiles * 128

typedef __hip_bfloat16 bf16;
typedef short bf16x8 __attribute__((ext_vector_type(8)));
typedef float f32x4 __attribute__((ext_vector_type(4)));

#define MFMA(a,b,c) __builtin_amdgcn_mfma_f32_16x16x32_bf16(a,b,c,0,0,0)

__device__ __forceinline__ float b2f(bf16 v){ return __bfloat162float(v); }
__device__ __forceinline__ bf16  f2b(float v){ return __float2bfloat16(v); }
__device__ __forceinline__ float us2f(unsigned short u){
  union { unsigned int i; float f; } v; v.i = ((unsigned int)u) << 16; return v.f;
}
__device__ __forceinline__ float silu(float v){ return v / (1.f + __expf(-v)); }
__device__ __forceinline__ void split2(float v, bf16& h, bf16& l){ h = f2b(v); l = f2b(v - b2f(h)); }
__device__ __forceinline__ float rc(const bf16* __restrict__ h, const bf16* __restrict__ l, size_t i){
  return b2f(h[i]) + b2f(l[i]);
}
__device__ __forceinline__ void gload16(const bf16* g, bf16* l){
  __builtin_amdgcn_global_load_lds(
      (const __attribute__((address_space(1))) void*)g,
      (__attribute__((address_space(3))) void*)l, 16, 0, 0);
}

// ---------------- guard diagnostic ----------------
__global__ void k_fill(float* __restrict__ o, float v){ o[threadIdx.x] = v; }

// ---------------- fused weight conversions ----------------
__global__ __launch_bounds__(256) void k_split3(
    const float* __restrict__ s0, bf16* __restrict__ h0, bf16* __restrict__ l0,
    const float* __restrict__ s1, bf16* __restrict__ h1, bf16* __restrict__ l1,
    const float* __restrict__ s2, bf16* __restrict__ h2, bf16* __restrict__ l2){
  long i = ((long)blockIdx.x * 256 + threadIdx.x) * 4;
  const float* s; bf16 *dh, *dl; long off;
  if (i < 4194304L)            { s = s0; dh = h0; dl = l0; off = i; }
  else if (i < 6291456L)       { s = s1; dh = h1; dl = l1; off = i - 4194304L; }
  else                          { s = s2; dh = h2; dl = l2; off = i - 6291456L; }
  float4 v = *(const float4*)(s + off);
  split2(v.x, dh[off],   dl[off]);
  split2(v.y, dh[off+1], dl[off+1]);
  split2(v.z, dh[off+2], dl[off+2]);
  split2(v.w, dh[off+3], dl[off+3]);
}
__global__ __launch_bounds__(256) void k_f2bf6(
    const float* __restrict__ s0, bf16* __restrict__ d0,
    const float* __restrict__ s1, bf16* __restrict__ d1,
    const float* __restrict__ s2, bf16* __restrict__ d2,
    const float* __restrict__ s3, bf16* __restrict__ d3,
    const float* __restrict__ s4, bf16* __restrict__ d4,
    const float* __restrict__ s5, bf16* __restrict__ d5){
  long i = ((long)blockIdx.x * 256 + threadIdx.x) * 4;
  const float* s; bf16* d; long off;
  if (i < 8388608L)        { s = s0; d = d0; off = i; }
  else if (i < 16777216L)  { s = s1; d = d1; off = i - 8388608L; }
  else if (i < 25165824L)  { s = s2; d = d2; off = i - 16777216L; }
  else if (i < 27262976L)  { s = s3; d = d3; off = i - 25165824L; }
  else if (i < 29360128L)  { s = s4; d = d4; off = i - 27262976L; }
  else                      { s = s5; d = d5; off = i - 29360128L; }
  float4 v = *(const float4*)(s + off);
  d[off] = f2b(v.x); d[off+1] = f2b(v.y); d[off+2] = f2b(v.z); d[off+3] = f2b(v.w);
}
__global__ __launch_bounds__(256) void k_split_pad(const float* __restrict__ s, bf16* __restrict__ dh,
                                                   bf16* __restrict__ dl){
  int i = (blockIdx.x * 256 + threadIdx.x) * 4;
  int row = i >> 11;
  if (row < 96) {
    float4 v = *(const float4*)(s + i);
    split2(v.x, dh[i],   dl[i]);
    split2(v.y, dh[i+1], dl[i+1]);
    split2(v.z, dh[i+2], dl[i+2]);
    split2(v.w, dh[i+3], dl[i+3]);
  } else {
    bf16 z = f2b(0.f);
    dh[i]=z; dh[i+1]=z; dh[i+2]=z; dh[i+3]=z;
    dl[i]=z; dl[i+1]=z; dl[i+2]=z; dl[i+3]=z;
  }
}

__global__ void k_zero_counts(int* __restrict__ c){
  if (threadIdx.x < NE) c[threadIdx.x] = 0;
}

// ---------------- rmsnorm ----------------
template<bool HL>
__global__ __launch_bounds__(256) void k_rmsnorm(const float* __restrict__ x, const float* __restrict__ w,
                                                 bf16* __restrict__ oh, bf16* __restrict__ ol){
  int row = blockIdx.x;
  const float* xr = x + (size_t)row * Dz;
  int c4 = threadIdx.x * 4;
  float4 v = *(const float4*)(xr + c4);
  float ss = v.x*v.x + v.y*v.y + v.z*v.z + v.w*v.w;
  #pragma unroll
  for (int o = 32; o; o >>= 1) ss += __shfl_xor(ss, o);
  __shared__ float sred[4];
  if ((threadIdx.x & 63) == 0) sred[threadIdx.x >> 6] = ss;
  __syncthreads();
  float tot = sred[0] + sred[1] + sred[2] + sred[3];
  float sc = rsqrtf(tot * (1.f / Dz) + 1e-6f);
  float4 wv = *(const float4*)(w + c4);
  float o0 = v.x*sc*wv.x, o1 = v.y*sc*wv.y, o2 = v.z*sc*wv.z, o3 = v.w*sc*wv.w;
  size_t ci = (size_t)row * Dz + c4;
  if (HL) {
    split2(o0, oh[ci], ol[ci]);   split2(o1, oh[ci+1], ol[ci+1]);
    split2(o2, oh[ci+2], ol[ci+2]); split2(o3, oh[ci+3], ol[ci+3]);
  } else {
    oh[ci] = f2b(o0); oh[ci+1] = f2b(o1); oh[ci+2] = f2b(o2); oh[ci+3] = f2b(o3);
  }
}

// ======== 128x128 LDS-staged split GEMM body (3-term) ========
// DB=false: single-buffered (32KB LDS — best for in_proj occupancy)
// DB=true : 2-phase double-buffered (64KB LDS — best for other users)
// EPI 1: dual f32 store: col<2048 -> Cf, else Cf2 (inner ld 2048)   (in_proj)
// EPI 3: Cf = v + epi[ci]; EPI 4: Cf += v                           (out_proj)
// EPI 5: Cf[row*ldc+col] = softplus(v + epi[col])                   (dt_proj)
// EPI 6: hi/lo -> C1h/C1l (ldc=128); cols [64,96) also -> Cf[row*32+col-64]  (x_proj)
template<int EPI, bool DB>
__device__ __forceinline__ void sp128_body(
    int row0, int n00,
    const bf16* __restrict__ Ah, const bf16* __restrict__ Al, int lda,
    const bf16* __restrict__ Bh, const bf16* __restrict__ Bl, int ldb,
    bf16* __restrict__ C1h, bf16* __restrict__ C1l,
    float* __restrict__ Cf, float* __restrict__ Cf2, int ldc, int K,
    const float* __restrict__ epi)
{
  constexpr int NB = DB ? 2 : 1;
  __shared__ __align__(16) bf16 sAh[NB][4096], sAl[NB][4096], sBh[NB][4096], sBl[NB][4096];
  int tid = threadIdx.x;
  int lane = tid & 63, w = tid >> 6;
  int wr = (w >> 1) * 64, wc = (w & 1) * 64;
  int srow = w * 32 + (lane >> 2);
  int scol = (((lane & 3) ^ ((lane >> 2) & 3)) * 8);
  const bf16* pAh = Ah + (size_t)(row0 + srow) * lda + scol;
  const bf16* pAl = Al + (size_t)(row0 + srow) * lda + scol;
  const bf16* pBh = Bh + (size_t)(n00 + srow) * ldb + scol;
  const bf16* pBl = Bl + (size_t)(n00 + srow) * ldb + scol;
  int lr = lane & 15;
  int rk = (((lane >> 4) ^ (lane & 3)) * 8);
  f32x4 acc[4][4];
  #pragma unroll
  for (int i = 0; i < 4; ++i)
    #pragma unroll
    for (int j = 0; j < 4; ++j) acc[i][j] = {0.f,0.f,0.f,0.f};
  auto STAGE = [&](int buf, int kt){
    #pragma unroll
    for (int j = 0; j < 2; ++j) {
      int lb = (w * 128 + j * 64) * 8;
      size_t goa = (size_t)j * 16 * lda + kt;
      size_t gob = (size_t)j * 16 * ldb + kt;
      gload16(pAh + goa, &sAh[buf][lb]);
      gload16(pAl + goa, &sAl[buf][lb]);
      gload16(pBh + gob, &sBh[buf][lb]);
      gload16(pBl + gob, &sBl[buf][lb]);
    }
  };
  auto COMPUTE = [&](int buf){
    bf16x8 fa[4], fb[4], ft[4];
    #pragma unroll
    for (int i = 0; i < 4; ++i) {
      fa[i] = *(const bf16x8*)&sAh[buf][(wr + i*16 + lr) * 32 + rk];
      fb[i] = *(const bf16x8*)&sBh[buf][(wc + i*16 + lr) * 32 + rk];
    }
    #pragma unroll
    for (int mi = 0; mi < 4; ++mi)
      #pragma unroll
      for (int ni = 0; ni < 4; ++ni)
        acc[mi][ni] = MFMA(fa[mi], fb[ni], acc[mi][ni]);
    #pragma unroll
    for (int i = 0; i < 4; ++i) ft[i] = *(const bf16x8*)&sBl[buf][(wc + i*16 + lr) * 32 + rk];
    #pragma unroll
    for (int mi = 0; mi < 4; ++mi)
      #pragma unroll
      for (int ni = 0; ni < 4; ++ni)
        acc[mi][ni] = MFMA(fa[mi], ft[ni], acc[mi][ni]);
    #pragma unroll
    for (int i = 0; i < 4; ++i) ft[i] = *(const bf16x8*)&sAl[buf][(wr + i*16 + lr) * 32 + rk];
    #pragma unroll
    for (int mi = 0; mi < 4; ++mi)
      #pragma unroll
      for (int ni = 0; ni < 4; ++ni)
        acc[mi][ni] = MFMA(ft[mi], fb[ni], acc[mi][ni]);
  };
  if (DB) {
    STAGE(0, 0);
    __syncthreads();
    int cur = 0;
    for (int kt = 0; kt < K; kt += 32) {
      if (kt + 32 < K) STAGE(cur ^ 1, kt + 32);
      COMPUTE(cur);
      __syncthreads();
      cur ^= 1;
    }
  } else {
    for (int kt = 0; kt < K; kt += 32) {
      if (kt) __syncthreads();
      STAGE(0, kt);
      __syncthreads();
      COMPUTE(0);
    }
  }
  int crow = (lane >> 4) * 4, ccol = lane & 15;
  #pragma unroll
  for (int mi = 0; mi < 4; ++mi)
  #pragma unroll
  for (int ni = 0; ni < 4; ++ni)
  #pragma unroll
  for (int r = 0; r < 4; ++r) {
    int row = row0 + wr + mi * 16 + crow + r;
    int col = n00 + wc + ni * 16 + ccol;
    float v = acc[mi][ni][r];
    if (EPI == 1) {
      size_t ci = (size_t)row * 2048 + (col & 2047);
      if (col < 2048) Cf[ci] = v; else Cf2[ci] = v;
    } else if (EPI == 3) {
      size_t ci = (size_t)row * ldc + col;
      Cf[ci] = v + epi[ci];
    } else if (EPI == 4) {
      size_t ci = (size_t)row * ldc + col;
      Cf[ci] += v;
    } else if (EPI == 5) {
      float t = v + epi[col];
      Cf[(size_t)row * ldc + col] = (t > 20.f) ? t : log1pf(__expf(t));
    } else if (EPI == 6) {
      size_t ci = (size_t)row * 128 + col;
      split2(v, C1h[ci], C1l[ci]);
      if (col >= 64 && col < 96) Cf[(size_t)row * 32 + col - 64] = v;
    }
  }
}

// ---- named wrappers (plain 2D grids) ----
// in_proj split along N: part a covers cols [0,2048) (xzi), part b cols [2048,4096) (res)
__global__ __launch_bounds__(256) void k_inproj_a(
    const bf16* Ah, const bf16* Al, const bf16* Bh, const bf16* Bl,
    float* Cf, float* Cf2){
  sp128_body<1,false>(blockIdx.x*128, blockIdx.y*128, Ah, Al, Dz, Bh, Bl, Dz,
                      nullptr, nullptr, Cf, Cf2, 2048, Dz, nullptr);
}
__global__ __launch_bounds__(256) void k_inproj_b(
    const bf16* Ah, const bf16* Al, const bf16* Bh, const bf16* Bl,
    float* Cf, float* Cf2){
  sp128_body<1,false>(blockIdx.x*128, (16 + blockIdx.y)*128, Ah, Al, Dz, Bh, Bl, Dz,
                      nullptr, nullptr, Cf, Cf2, 2048, Dz, nullptr);
}
__global__ __launch_bounds__(256) void k_xproj(
    const bf16* Ah, const bf16* Al, const bf16* Bh, const bf16* Bl,
    bf16* C1h, bf16* C1l, float* Cf){
  sp128_body<6,true>(blockIdx.x*128, blockIdx.y*128, Ah, Al, DIz, Bh, Bl, DIz,
                     C1h, C1l, Cf, nullptr, 128, DIz, nullptr);
}
__global__ __launch_bounds__(256) void k_dtproj(
    const bf16* Ah, const bf16* Al, const bf16* Bh, const bf16* Bl,
    float* Cf, const float* epi){
  sp128_body<5,true>(blockIdx.x*128, blockIdx.y*128, Ah, Al, 128, Bh, Bl, DTRz,
                     nullptr, nullptr, Cf, nullptr, NDH, DTRz, epi);
}
template<int EPI>
__global__ __launch_bounds__(256) void k_outproj(
    const bf16* Ah, const bf16* Al, const bf16* Bh, const bf16* Bl,
    float* Cf, const float* epi){
  sp128_body<EPI,true>(blockIdx.x*128, blockIdx.y*128, Ah, Al, NDH, Bh, Bl, DIz,
                       nullptr, nullptr, Cf, nullptr, Dz, NDH, epi);
}

// ======== 128x128 plain GEMM body, 2-phase double-buffered ========
// EPI 4 = v*wslot[row] (guarded) -> bf16; EPI 5 = f32 +=; EPI 6 = bf16 store
// GATHER: A rows indirected through toks (guarded by counts)
template<int EPI, bool ROUTED, bool GATHER>
__device__ __forceinline__ void gemm128_body(
    int row0, int n00, int e,
    const bf16* __restrict__ A, int lda,
    const bf16* __restrict__ Bm, int ldb,
    void* __restrict__ Cp, int ldc, int K,
    const float* __restrict__ epi,
    const int* __restrict__ offs, const int* __restrict__ toks,
    const int* __restrict__ counts)
{
  __shared__ __align__(16) bf16 sA[2][4096], sB[2][4096];
  int tid = threadIdx.x;
  int lane = tid & 63, w = tid >> 6;
  int wr = (w >> 1) * 64, wc = (w & 1) * 64;
  int srow = w * 32 + (lane >> 2);
  int scol = (((lane & 3) ^ ((lane >> 2) & 3)) * 8);
  size_t arow[2];
  #pragma unroll
  for (int j = 0; j < 2; ++j) {
    int r = row0 + srow + j * 16;
    if (GATHER) {
      int tk = toks[r];
      if (r - offs[e] >= counts[e]) tk = 0;
      tk &= (Tz - 1);
      arow[j] = (size_t)tk * lda;
    } else {
      arow[j] = (size_t)r * lda;
    }
  }
  const bf16* pB = Bm + (size_t)(n00 + srow) * ldb + scol;
  int lr = lane & 15;
  int rk = (((lane >> 4) ^ (lane & 3)) * 8);
  f32x4 acc[4][4];
  #pragma unroll
  for (int i = 0; i < 4; ++i)
    #pragma unroll
    for (int j = 0; j < 4; ++j) acc[i][j] = {0.f,0.f,0.f,0.f};
  auto STAGE = [&](int buf, int kt){
    #pragma unroll
    for (int j = 0; j < 2; ++j) {
      int lb = (w * 128 + j * 64) * 8;
      gload16(A + arow[j] + scol + kt, &sA[buf][lb]);
      gload16(pB + (size_t)j * 16 * ldb + kt, &sB[buf][lb]);
    }
  };
  STAGE(0, 0);
  __syncthreads();
  int cur = 0;
  for (int kt = 0; kt < K; kt += 32) {
    if (kt + 32 < K) STAGE(cur ^ 1, kt + 32);
    bf16x8 fa[4], fb[4];
    #pragma unroll
    for (int i = 0; i < 4; ++i) {
      fa[i] = *(const bf16x8*)&sA[cur][(wr + i*16 + lr) * 32 + rk];
      fb[i] = *(const bf16x8*)&sB[cur][(wc + i*16 + lr) * 32 + rk];
    }
    #pragma unroll
    for (int mi = 0; mi < 4; ++mi)
      #pragma unroll
      for (int ni = 0; ni < 4; ++ni)
        acc[mi][ni] = MFMA(fa[mi], fb[ni], acc[mi][ni]);
    __syncthreads();
    cur ^= 1;
  }
  int crow = (lane >> 4) * 4, ccol = lane & 15;
  int base_e = ROUTED ? offs[e] : 0;
  int cnt_e  = ROUTED ? counts[e] : 0;
  #pragma unroll
  for (int mi = 0; mi < 4; ++mi)
  #pragma unroll
  for (int ni = 0; ni < 4; ++ni)
  #pragma unroll
  for (int r = 0; r < 4; ++r) {
    int row = row0 + wr + mi * 16 + crow + r;
    int col = n00 + wc + ni * 16 + ccol;
    size_t ci = (size_t)row * ldc + col;
    float v = acc[mi][ni][r];
    if (EPI == 4) {
      float wv = (row - base_e < cnt_e) ? epi[row] : 0.f;
      ((bf16*)Cp)[ci] = f2b(v * wv);
    } else if (EPI == 5) ((float*)Cp)[ci] += v;
    else if (EPI == 6) ((bf16*)Cp)[ci] = f2b(v);
  }
}

// expert-tile map helper for routed kernels
__device__ __forceinline__ bool expert_map(const int* offs, int& e, int& row0){
  int bid = blockIdx.x, cum = 0; e = -1; row0 = 0;
  #pragma unroll
  for (int i = 0; i < 8; ++i) {
    int tiles = (offs[i+1] - offs[i]) >> 7;
    if (e < 0 && bid < cum + tiles) { e = i; row0 = offs[i] + ((bid - cum) << 7); }
    cum += tiles;
  }
  return e >= 0;
}

// merged routed GLU GEMM: grid.y 0-7 -> gate (G), 8-15 -> up (U)
__global__ __launch_bounds__(256) void k_moe_glu_r(
    const bf16* A, const bf16* Wg, const bf16* Wu, bf16* G, bf16* U,
    const int* offs, const int* toks, const int* counts){
  int e, row0;
  if (!expert_map(offs, e, row0)) return;
  int by = blockIdx.y;
  const bf16* Bw = (by < 8) ? Wg : Wu;
  bf16* Cp = (by < 8) ? G : U;
  int n00 = (by & 7) * 128;
  gemm128_body<6,true,true>(row0, n00, e, A, Dz, Bw + (size_t)e*Fz*Dz, Dz,
                            Cp, Fz, Dz, nullptr, offs, toks, counts);
}
// merged shared GLU GEMM: grid.y 0-15 -> gate (G), 16-31 -> up (U)
__global__ __launch_bounds__(256) void k_moe_glu_s(
    const bf16* A, const bf16* Wg, const bf16* Wu, bf16* G, bf16* U){
  int by = blockIdx.y;
  const bf16* Bw = (by < 16) ? Wg : Wu;
  bf16* Cp = (by < 16) ? G : U;
  int n00 = (by & 15) * 128;
  gemm128_body<6,false,false>(blockIdx.x*128, n00, 0, A, Dz, Bw, Dz,
                              Cp, FSz, Dz, nullptr, nullptr, nullptr, nullptr);
}
__global__ __launch_bounds__(256) void k_down_routed(
    const bf16* A, const bf16* Bw, bf16* Cp, const float* epi,
    const int* offs, const int* counts){
  int e, row0;
  if (!expert_map(offs, e, row0)) return;
  gemm128_body<4,true,false>(row0, blockIdx.y*128, e, A, Fz, Bw + (size_t)e*Dz*Fz, Fz,
                             Cp, Dz, Fz, epi, offs, nullptr, counts);
}
__global__ __launch_bounds__(256) void k_down_shared(
    const bf16* A, const bf16* Bw, float* Cp){
  gemm128_body<5,false,false>(blockIdx.x*128, blockIdx.y*128, 0, A, FSz, Bw, FSz,
                              Cp, Dz, FSz, nullptr, nullptr, nullptr, nullptr);
}

// ---------------- silu-mul: G = silu(G) * U  (bf16x8 vectorized, in place) ----------------
__global__ __launch_bounds__(256) void k_silumul(bf16* __restrict__ G, const bf16* __restrict__ U){
  long i = ((long)blockIdx.x * 256 + threadIdx.x) * 8;
  bf16x8 gv = *(const bf16x8*)&G[i];
  bf16x8 uv = *(const bf16x8*)&U[i];
  bf16 ov[8];
  #pragma unroll
  for (int k2 = 0; k2 < 8; ++k2) {
    float g = us2f((unsigned short)gv[k2]);
    float u = us2f((unsigned short)uv[k2]);
    ov[k2] = f2b(silu(g) * u);
  }
  *(bf16x8*)&G[i] = *(const bf16x8*)ov;
}

// ---------------- causal depthwise conv (4 taps) + silu; 4 rows per thread ----------------
__global__ __launch_bounds__(256) void k_conv4(const float* __restrict__ xz,
                                               const float* __restrict__ cw, const float* __restrict__ cb,
                                               bf16* __restrict__ oh, bf16* __restrict__ ol){
  int d = blockIdx.x * 256 + threadIdx.x;
  int r0 = blockIdx.y * 4;
  int s0 = r0 & (Sz - 1);
  size_t base = (size_t)r0 * DIz + d;
  float w0 = cw[d*4+0], w1 = cw[d*4+1], w2 = cw[d*4+2], w3 = cw[d*4+3], bb = cb[d];
  float a  = (s0 == 0) ? 0.f : xz[base - 3*DIz];
  float b_ = (s0 == 0) ? 0.f : xz[base - 2*DIz];
  float c  = (s0 == 0) ? 0.f : xz[base - 1*DIz];
  float x0 = xz[base], x1 = xz[base + DIz], x2 = xz[base + 2*DIz], x3 = xz[base + 3*DIz];
  float v0 = bb + w0*a  + w1*b_ + w2*c  + w3*x0;
  float v1 = bb + w0*b_ + w1*c  + w2*x0 + w3*x1;
  float v2 = bb + w0*c  + w1*x0 + w2*x1 + w3*x2;
  float v3 = bb + w0*x0 + w1*x1 + w2*x2 + w3*x3;
  float o0 = v0 / (1.f + __expf(-v0));
  float o1 = v1 / (1.f + __expf(-v1));
  float o2 = v2 / (1.f + __expf(-v2));
  float o3 = v3 / (1.f + __expf(-v3));
  split2(o0, oh[base],         ol[base]);
  split2(o1, oh[base + DIz],   ol[base + DIz]);
  split2(o2, oh[base + 2*DIz], ol[base + 2*DIz]);
  split2(o3, oh[base + 3*DIz], ol[base + 3*DIz]);
}

// ---------------- chunked selective scan: thread-per-d, h[16] in registers ----------------
__global__ __launch_bounds__(256) void k_scan1r(const float* __restrict__ dtf,
                                                const bf16* __restrict__ xih, const bf16* __restrict__ xil,
                                                const float* __restrict__ xdf, const float* __restrict__ A_log,
                                                float* __restrict__ P, float* __restrict__ R){
  int b = blockIdx.y, c = blockIdx.z;
  int d = blockIdx.x * 256 + threadIdx.x;
  __shared__ float sBC[CL2*32];
  int s0 = c * CL2;
  for (int i = threadIdx.x; i < CL2*32; i += 256)
    sBC[i] = xdf[((size_t)b*Sz + s0 + (i >> 5)) * 32 + (i & 31)];
  float Adn[16];
  #pragma unroll
  for (int n = 0; n < 16; ++n) Adn[n] = -__expf(A_log[d*16+n]);
  __syncthreads();
  float h[16];
  #pragma unroll
  for (int n = 0; n < 16; ++n) h[n] = 0.f;
  float sdt = 0.f;
  for (int s = 0; s < CL2; ++s) {
    size_t row = (size_t)b * Sz + s0 + s;
    float dtv = dtf[row * NDH + d];
    float xiv = rc(xih, xil, row * DIz + d);
    float kb = dtv * xiv;
    const float* bc = &sBC[s*32];
    sdt += dtv;
    #pragma unroll
    for (int n = 0; n < 16; ++n) {
      float da = __expf(dtv * Adn[n]);
      h[n] = da * h[n] + kb * bc[n];
    }
  }
  size_t idx = (((size_t)c * Bz + b) * NDH + d) * 16;
  #pragma unroll
  for (int n = 0; n < 16; ++n) { P[idx+n] = __expf(sdt * Adn[n]); R[idx+n] = h[n]; }
}
__global__ __launch_bounds__(256) void k_scan2(const float* __restrict__ P, const float* __restrict__ R,
                                               float* __restrict__ Hin){
  int i = blockIdx.x * 256 + threadIdx.x;
  float h = 0.f;
  #pragma unroll 4
  for (int c = 0; c < NCH2; ++c) {
    size_t idx = (size_t)c * (Bz * NDH * 16) + i;
    Hin[idx] = h;
    h = P[idx] * h + R[idx];
  }
}
__global__ __launch_bounds__(256) void k_scan3r(const float* __restrict__ dtf,
                                                const bf16* __restrict__ xih, const bf16* __restrict__ xil,
                                                const float* __restrict__ xdf, const float* __restrict__ resf,
                                                const float* __restrict__ A_log, const float* __restrict__ Dsk,
                                                const float* __restrict__ Hin,
                                                bf16* __restrict__ yh, bf16* __restrict__ yl){
  int b = blockIdx.y, c = blockIdx.z;
  int d = blockIdx.x * 256 + threadIdx.x;
  __shared__ float sBC[CL2*32];
  int s0 = c * CL2;
  for (int i = threadIdx.x; i < CL2*32; i += 256)
    sBC[i] = xdf[((size_t)b*Sz + s0 + (i >> 5)) * 32 + (i & 31)];
  float Adn[16];
  #pragma unroll
  for (int n = 0; n < 16; ++n) Adn[n] = -__expf(A_log[d*16+n]);
  float Dv = Dsk[d];
  __syncthreads();
  float h[16];
  size_t hidx = (((size_t)c * Bz + b) * NDH + d) * 16;
  #pragma unroll
  for (int n = 0; n < 16; ++n) h[n] = Hin[hidx+n];
  for (int s = 0; s < CL2; ++s) {
    size_t row = (size_t)b * Sz + s0 + s;
    float dtv = dtf[row * NDH + d];
    float xiv = rc(xih, xil, row * DIz + d);
    float kb = dtv * xiv;
    const float* bc = &sBC[s*32];
    float acc = 0.f;
    #pragma unroll
    for (int n = 0; n < 16; ++n) {
      float da = __expf(dtv * Adn[n]);
      h[n] = da * h[n] + kb * bc[n];
      acc = fmaf(h[n], bc[16+n], acc);
    }
    float resv = resf[row * DIz + d];
    float yv = (acc + xiv * Dv) * (resv / (1.f + __expf(-resv)));
    split2(yv, yh[row * NDH + d], yl[row * NDH + d]);
  }
}

// ---------------- MoE gate: 4 tokens/block, NO atomics ----------------
__global__ __launch_bounds__(256) void k_gate(const float* __restrict__ m, const float* __restrict__ nw,
                                              const float* __restrict__ gw, const float* __restrict__ gb,
                                              int* __restrict__ topi, float* __restrict__ topw){
  int t = blockIdx.x * 4 + (threadIdx.x >> 6);
  int lane = threadIdx.x & 63;
  const float* xr = m + (size_t)t * Dz;
  float xv[16];
  float ss = 0.f;
  #pragma unroll
  for (int j = 0; j < 16; ++j) { xv[j] = xr[lane + j * 64]; ss += xv[j] * xv[j]; }
  #pragma unroll
  for (int o = 32; o; o >>= 1) ss += __shfl_xor(ss, o);
  float sc = rsqrtf(ss * (1.f / Dz) + 1e-6f);
  #pragma unroll
  for (int j = 0; j < 16; ++j) xv[j] *= sc * nw[lane + j * 64];
  float acc[8] = {0.f,0.f,0.f,0.f,0.f,0.f,0.f,0.f};
  #pragma unroll
  for (int j = 0; j < 16; ++j) {
    #pragma unroll
    for (int e = 0; e < 8; ++e) acc[e] += xv[j] * gw[e * Dz + lane + j * 64];
  }
  #pragma unroll
  for (int e = 0; e < 8; ++e) {
    float v = acc[e];
    #pragma unroll
    for (int o = 32; o; o >>= 1) v += __shfl_xor(v, o);
    acc[e] = v;
  }
  if (lane == 0) {
    float mx = acc[0];
    #pragma unroll
    for (int e = 1; e < 8; ++e) mx = fmaxf(mx, acc[e]);
    float scr[8]; float sum = 0.f;
    #pragma unroll
    for (int e = 0; e < 8; ++e) { scr[e] = expf(acc[e] - mx); sum += scr[e]; }
    float inv = 1.f / sum;
    #pragma unroll
    for (int e = 0; e < 8; ++e) scr[e] *= inv;
    int i0 = 0; float b0 = -1e30f;
    #pragma unroll
    for (int e = 0; e < 8; ++e) { float kv = scr[e] + gb[e]; if (kv > b0) { b0 = kv; i0 = e; } }
    int i1 = -1; float b1 = -1e30f;
    #pragma unroll
    for (int e = 0; e < 8; ++e) { if (e == i0) continue; float kv = scr[e] + gb[e]; if (kv > b1) { b1 = kv; i1 = e; } }
    float w0 = scr[i0], w1 = scr[i1];
    float wn = 1.f / (w0 + w1 + 1e-9f);
    topi[t*2] = i0; topi[t*2+1] = i1;
    topw[t*2] = w0 * wn; topw[t*2+1] = w1 * wn;
  }
}

// ---------------- expert count: LDS histogram, 8 global atomics per block ----------------
__global__ __launch_bounds__(256) void k_count(const int* __restrict__ topi, int* __restrict__ counts){
  __shared__ int cnt[NE];
  int tid = threadIdx.x;
  if (tid < NE) cnt[tid] = 0;
  __syncthreads();
  int i = blockIdx.x * 256 + tid;
  atomicAdd(&cnt[topi[i]], 1);
  __syncthreads();
  if (tid < NE) atomicAdd(&counts[tid], cnt[tid]);
}

__global__ void k_offs(const int* __restrict__ counts, int* __restrict__ offs, int* __restrict__ fill){
  if (threadIdx.x == 0) {
    int o = 0;
    for (int e = 0; e < 8; ++e) { offs[e] = o; o += ((counts[e] + 127) & ~127); }
    offs[8] = o;
  }
  if (threadIdx.x < 8) fill[threadIdx.x] = 0;
}

// ---------------- scatter: per-block LDS positions + 8 reservation atomics ----------------
__global__ __launch_bounds__(256) void k_scatter(const int* __restrict__ topi, const float* __restrict__ topw,
                                                 const int* __restrict__ offs, int* __restrict__ fill,
                                                 int* __restrict__ toks, float* __restrict__ wslot,
                                                 int* __restrict__ slot_of){
  __shared__ int cnt[NE], basee[NE];
  int tid = threadIdx.x;
  if (tid < NE) cnt[tid] = 0;
  __syncthreads();
  int i = blockIdx.x * 256 + tid;
  int e = topi[i];
  int pos = atomicAdd(&cnt[e], 1);
  __syncthreads();
  if (tid < NE) basee[tid] = atomicAdd(&fill[tid], cnt[tid]);
  __syncthreads();
  int slot = offs[e] + basee[e] + pos;
  toks[slot] = i >> 1;
  wslot[slot] = topw[i];
  slot_of[i] = slot;
}

// ---------------- final combine: out = m + down0 + down1 ----------------
__global__ __launch_bounds__(256) void k_combine(const float* __restrict__ m,
                                                 const bf16* __restrict__ Hd, const int* __restrict__ slot_of,
                                                 float* __restrict__ out){
  int t = blockIdx.x;
  int ci = threadIdx.x * 4;
  int s0 = slot_of[t*2], s1 = slot_of[t*2+1];
  size_t base = (size_t)t * Dz + ci;
  float4 mv = *(const float4*)(m + base);
  ushort4 h0 = *(const ushort4*)((const unsigned short*)Hd + (size_t)s0 * Dz + ci);
  ushort4 h1 = *(const ushort4*)((const unsigned short*)Hd + (size_t)s1 * Dz + ci);
  out[base+0] = mv.x + us2f(h0.x) + us2f(h1.x);
  out[base+1] = mv.y + us2f(h0.y) + us2f(h1.y);
  out[base+2] = mv.z + us2f(h0.z) + us2f(h1.z);
  out[base+3] = mv.w + us2f(h0.w) + us2f(h1.w);
}

extern "C" void kernel_launch(void* const* d_in, const int* in_sizes, int n_in,
                              void* d_out, int out_size, void* d_ws, size_t ws_size,
                              hipStream_t stream) {
  (void)in_sizes; (void)n_in; (void)out_size;
  const float* x         = (const float*)d_in[0];
  const float* norm_w    = (const float*)d_in[1];
  const float* in_proj   = (const float*)d_in[2];
  const float* conv_w    = (const float*)d_in[3];
  const float* conv_b    = (const float*)d_in[4];
  const float* x_proj    = (const float*)d_in[5];
  const float* dt_proj   = (const float*)d_in[6];
  const float* dt_proj_b = (const float*)d_in[7];
  const float* A_log     = (const float*)d_in[8];
  const float* D_skip    = (const float*)d_in[9];
  const float* out_proj  = (const float*)d_in[10];
  const float* gate_w    = (const float*)d_in[11];
  const float* gate_b    = (const float*)d_in[12];
  const float* w_gate    = (const float*)d_in[13];
  const float* w_up      = (const float*)d_in[14];
  const float* w_down    = (const float*)d_in[15];
  const float* ws_gate   = (const float*)d_in[16];
  const float* ws_up     = (const float*)d_in[17];
  const float* ws_down   = (const float*)d_in[18];
  float* out = (float*)d_out;

  const size_t MB = 1024 * 1024;
  const size_t NEED = 253 * MB;
  if (ws_size < NEED) {
    k_fill<<<dim3(1), dim3(256), 0, stream>>>(out, (float)(ws_size / MB));
    fprintf(stderr, "kernel_launch: ws_size=%zu < needed=%zu\n", ws_size, NEED);
    return;
  }
  char* P = (char*)d_ws;
  // ---- phase A layout ----
  float* res_f = (float*)(P + 0*MB);
  bf16*  xi_h  = (bf16*)(P + 64*MB);
  bf16*  xi_l  = (bf16*)(P + 96*MB);
  bf16*  xd_h  = (bf16*)(P + 128*MB);
  bf16*  xd_l  = (bf16*)(P + 130*MB);
  float* xdf   = (float*)(P + 132*MB);
  bf16*  xph   = (bf16*)(P + 133*MB);
  bf16*  xpl   = (bf16*)(P + 133*MB + 512*1024);
  bf16*  dph   = (bf16*)(P + 134*MB);
  bf16*  dpl   = (bf16*)(P + 134*MB + 256*1024);
  bf16*  oph   = (bf16*)(P + 135*MB);
  bf16*  opl   = (bf16*)(P + 139*MB);
  float* dtf   = (float*)(P + 144*MB);
  float* scanH = (float*)(P + 176*MB);
  bf16*  y_h   = (bf16*)(P + 188*MB);
  float* scanP = (float*)(P + 192*MB);
  float* scanR = (float*)(P + 200*MB);
  bf16*  y_l   = (bf16*)(P + 204*MB);
  float* mbuf  = (float*)(P + 220*MB);
  // transients:
  bf16*  nrm_h = (bf16*)(P + 144*MB);
  bf16*  nrm_l = (bf16*)(P + 160*MB);
  bf16*  iph   = (bf16*)(P + 176*MB);
  bf16*  ipl   = (bf16*)(P + 184*MB);
  float* xzi_f = (float*)(P + 192*MB);
  // ---- phase B (MoE) overlay ----
  bf16* n2b   = (bf16*)(P + 0*MB);
  bf16* wgh   = (bf16*)(P + 16*MB);
  bf16* wuh   = (bf16*)(P + 32*MB);
  bf16* wdh   = (bf16*)(P + 48*MB);
  bf16* wsg   = (bf16*)(P + 64*MB);
  bf16* wsu   = (bf16*)(P + 68*MB);
  bf16* wsd   = (bf16*)(P + 72*MB);
  bf16* Hbuf  = (bf16*)(P + 76*MB);    // G (routed) then H after silumul; 34MB
  bf16* Hd    = (bf16*)(P + 110*MB);   // 34MB
  bf16* Sh    = (bf16*)(P + 144*MB);   // G (shared) then H; 32MB
  bf16* Utmp  = (bf16*)(P + 176*MB);   // 34MB (over dead scan/y region)
  char* Rt    = P + 252*MB;
  int*   counts  = (int*)(Rt);
  int*   offsb   = (int*)(Rt + 64);
  int*   fill    = (int*)(Rt + 128);
  int*   topi    = (int*)(Rt + 1024);
  float* topw    = (float*)(Rt + 1024 + 65536);
  int*   toks    = (int*)(Rt + 1024 + 2*65536);
  float* wslot   = (float*)(Rt + 1024 + 2*65536 + 69632);
  int*   slot_of = (int*)(Rt + 1024 + 2*65536 + 2*69632);

  // fused mamba weight splits + x_proj pad
  k_split3<<<dim3(6272), dim3(256), 0, stream>>>(in_proj, iph, ipl, out_proj, oph, opl, dt_proj, dph, dpl);
  k_split_pad<<<dim3(256), dim3(256), 0, stream>>>(x_proj, xph, xpl);

  // 1. rmsnorm(x) -> normed hi/lo
  k_rmsnorm<true><<<dim3(Tz), dim3(256), 0, stream>>>(x, norm_w, nrm_h, nrm_l);
  // 2. in_proj split along N: a = xzi cols, b = res cols
  k_inproj_a<<<dim3(Tz/128, 16), dim3(256), 0, stream>>>(nrm_h, nrm_l, iph, ipl, xzi_f, res_f);
  k_inproj_b<<<dim3(Tz/128, 16), dim3(256), 0, stream>>>(nrm_h, nrm_l, iph, ipl, xzi_f, res_f);
  // 3. causal conv + silu -> xi hi/lo
  k_conv4<<<dim3(DIz/256, Tz/4), dim3(256), 0, stream>>>(xzi_f, conv_w, conv_b, xi_h, xi_l);
  // 4. x_proj -> xd hi/lo + xdf f32 (B|C)
  k_xproj<<<dim3(Tz/128, 1), dim3(256), 0, stream>>>(xi_h, xi_l, xph, xpl, xd_h, xd_l, xdf);

  // 5-7. per d-half: dt_proj -> scan -> out_proj partial
  for (int h = 0; h < 2; ++h) {
    int d0 = h * NDH;
    k_dtproj<<<dim3(Tz/128, NDH/128), dim3(256), 0, stream>>>(
        xd_h, xd_l, dph + (size_t)d0*DTRz, dpl + (size_t)d0*DTRz, dtf, dt_proj_b + d0);
    k_scan1r<<<dim3(NDH/256, Bz, NCH2), dim3(256), 0, stream>>>(
        dtf, xi_h + d0, xi_l + d0, xdf, A_log + (size_t)d0*DSz, scanP, scanR);
    k_scan2<<<dim3(Bz*NDH*DSz/256), dim3(256), 0, stream>>>(scanP, scanR, scanH);
    k_scan3r<<<dim3(NDH/256, Bz, NCH2), dim3(256), 0, stream>>>(
        dtf, xi_h + d0, xi_l + d0, xdf, res_f + d0, A_log + (size_t)d0*DSz,
        D_skip + d0, scanH, y_h, y_l);
    if (h == 0)
      k_outproj<3><<<dim3(Tz/128, Dz/128), dim3(256), 0, stream>>>(
          y_h, y_l, oph + d0, opl + d0, mbuf, x);
    else
      k_outproj<4><<<dim3(Tz/128, Dz/128), dim3(256), 0, stream>>>(
          y_h, y_l, oph + d0, opl + d0, mbuf, nullptr);
  }

  // MoE weight conversion
  k_f2bf6<<<dim3(30720), dim3(256), 0, stream>>>(
      w_gate, wgh, w_up, wuh, w_down, wdh, ws_gate, wsg, ws_up, wsu, ws_down, wsd);
  // 8. rmsnorm(m) -> n2 bf16
  k_rmsnorm<false><<<dim3(Tz), dim3(256), 0, stream>>>(mbuf, norm_w, n2b, nullptr);
  // 9. gate (no atomics) + count + routing
  k_gate<<<dim3(Tz/4), dim3(256), 0, stream>>>(mbuf, norm_w, gate_w, gate_b, topi, topw);
  k_zero_counts<<<dim3(1), dim3(64), 0, stream>>>(counts);
  k_count<<<dim3(Tz*2/256), dim3(256), 0, stream>>>(topi, counts);
  k_offs<<<dim3(1), dim3(64), 0, stream>>>(counts, offsb, fill);
  k_scatter<<<dim3(Tz*2/256), dim3(256), 0, stream>>>(topi, topw, offsb, fill, toks, wslot, slot_of);
  // 10. routed experts: merged gate|up GEMM, silumul, down
  k_moe_glu_r<<<dim3(SLOTCAP/128, 16), dim3(256), 0, stream>>>(
      n2b, wgh, wuh, Hbuf, Utmp, offsb, toks, counts);
  k_silumul<<<dim3((unsigned)((size_t)SLOTCAP*Fz/2048)), dim3(256), 0, stream>>>(Hbuf, Utmp);
  k_down_routed<<<dim3(SLOTCAP/128, Dz/128), dim3(256), 0, stream>>>(
      Hbuf, wdh, Hd, wslot, offsb, counts);
  // 11. shared expert: merged gate|up GEMM, silumul
  k_moe_glu_s<<<dim3(Tz/128, 32), dim3(256), 0, stream>>>(n2b, wsg, wsu, Sh, Utmp);
  k_silumul<<<dim3((unsigned)((size_t)Tz*FSz/2048)), dim3(256), 0, stream>>>(Sh, Utmp);
  // 12. combine -> out = m + routed
  k_combine<<<dim3(Tz), dim3(256), 0, stream>>>(mbuf, Hd, slot_of, out);
  // 13. shared down: out += Sh @ ws_down^T
  k_down_shared<<<dim3(Tz/128, Dz/128), dim3(256), 0, stream>>>(Sh, wsd, out);
}

// Round 18
// 1198.022 us; speedup vs baseline: 1.0313x; 1.0313x over previous
//
#include <hip/hip_runtime.h>
#include <hip/hip_bf16.h>
#include <cstdio>

#define Bz 2
#define Sz 4096
#define Dz 1024
#define DIz 2048
#define DSz 16
#define DTRz 64
#define NE 8
#define Fz 1024
#define FSz 2048
#define Tz (Bz*Sz)            // 8192 tokens
#define NDH 1024              // d-half width
#define NCH2 64
#define CL2 (Sz/NCH2)         // 64
#define SLOTCAP 17408         // 136 tiles * 128

typedef __hip_bfloat16 bf16;
typedef short bf16x8 __attribute__((ext_vector_type(8)));
typedef float f32x4 __attribute__((ext_vector_type(4)));

#define MFMA(a,b,c) __builtin_amdgcn_mfma_f32_16x16x32_bf16(a,b,c,0,0,0)

__device__ __forceinline__ float b2f(bf16 v){ return __bfloat162float(v); }
__device__ __forceinline__ bf16  f2b(float v){ return __float2bfloat16(v); }
__device__ __forceinline__ float us2f(unsigned short u){
  union { unsigned int i; float f; } v; v.i = ((unsigned int)u) << 16; return v.f;
}
__device__ __forceinline__ float silu(float v){ return v / (1.f + __expf(-v)); }
__device__ __forceinline__ void split2(float v, bf16& h, bf16& l){ h = f2b(v); l = f2b(v - b2f(h)); }
__device__ __forceinline__ float rc(const bf16* __restrict__ h, const bf16* __restrict__ l, size_t i){
  return b2f(h[i]) + b2f(l[i]);
}
__device__ __forceinline__ void gload16(const bf16* g, bf16* l){
  __builtin_amdgcn_global_load_lds(
      (const __attribute__((address_space(1))) void*)g,
      (__attribute__((address_space(3))) void*)l, 16, 0, 0);
}

// ---------------- guard diagnostic ----------------
__global__ void k_fill(float* __restrict__ o, float v){ o[threadIdx.x] = v; }

// ---------------- fused weight conversions ----------------
__global__ __launch_bounds__(256) void k_split3(
    const float* __restrict__ s0, bf16* __restrict__ h0, bf16* __restrict__ l0,
    const float* __restrict__ s1, bf16* __restrict__ h1, bf16* __restrict__ l1,
    const float* __restrict__ s2, bf16* __restrict__ h2, bf16* __restrict__ l2){
  long i = ((long)blockIdx.x * 256 + threadIdx.x) * 4;
  const float* s; bf16 *dh, *dl; long off;
  if (i < 4194304L)            { s = s0; dh = h0; dl = l0; off = i; }
  else if (i < 6291456L)       { s = s1; dh = h1; dl = l1; off = i - 4194304L; }
  else                          { s = s2; dh = h2; dl = l2; off = i - 6291456L; }
  float4 v = *(const float4*)(s + off);
  split2(v.x, dh[off],   dl[off]);
  split2(v.y, dh[off+1], dl[off+1]);
  split2(v.z, dh[off+2], dl[off+2]);
  split2(v.w, dh[off+3], dl[off+3]);
}
__global__ __launch_bounds__(256) void k_f2bf6(
    const float* __restrict__ s0, bf16* __restrict__ d0,
    const float* __restrict__ s1, bf16* __restrict__ d1,
    const float* __restrict__ s2, bf16* __restrict__ d2,
    const float* __restrict__ s3, bf16* __restrict__ d3,
    const float* __restrict__ s4, bf16* __restrict__ d4,
    const float* __restrict__ s5, bf16* __restrict__ d5){
  long i = ((long)blockIdx.x * 256 + threadIdx.x) * 4;
  const float* s; bf16* d; long off;
  if (i < 8388608L)        { s = s0; d = d0; off = i; }
  else if (i < 16777216L)  { s = s1; d = d1; off = i - 8388608L; }
  else if (i < 25165824L)  { s = s2; d = d2; off = i - 16777216L; }
  else if (i < 27262976L)  { s = s3; d = d3; off = i - 25165824L; }
  else if (i < 29360128L)  { s = s4; d = d4; off = i - 27262976L; }
  else                      { s = s5; d = d5; off = i - 29360128L; }
  float4 v = *(const float4*)(s + off);
  d[off] = f2b(v.x); d[off+1] = f2b(v.y); d[off+2] = f2b(v.z); d[off+3] = f2b(v.w);
}
__global__ __launch_bounds__(256) void k_split_pad(const float* __restrict__ s, bf16* __restrict__ dh,
                                                   bf16* __restrict__ dl){
  int i = (blockIdx.x * 256 + threadIdx.x) * 4;
  int row = i >> 11;
  if (row < 96) {
    float4 v = *(const float4*)(s + i);
    split2(v.x, dh[i],   dl[i]);
    split2(v.y, dh[i+1], dl[i+1]);
    split2(v.z, dh[i+2], dl[i+2]);
    split2(v.w, dh[i+3], dl[i+3]);
  } else {
    bf16 z = f2b(0.f);
    dh[i]=z; dh[i+1]=z; dh[i+2]=z; dh[i+3]=z;
    dl[i]=z; dl[i+1]=z; dl[i+2]=z; dl[i+3]=z;
  }
}

__global__ void k_zero_counts(int* __restrict__ c){
  if (threadIdx.x < NE) c[threadIdx.x] = 0;
}

// ---------------- rmsnorm ----------------
template<bool HL>
__global__ __launch_bounds__(256) void k_rmsnorm(const float* __restrict__ x, const float* __restrict__ w,
                                                 bf16* __restrict__ oh, bf16* __restrict__ ol){
  int row = blockIdx.x;
  const float* xr = x + (size_t)row * Dz;
  int c4 = threadIdx.x * 4;
  float4 v = *(const float4*)(xr + c4);
  float ss = v.x*v.x + v.y*v.y + v.z*v.z + v.w*v.w;
  #pragma unroll
  for (int o = 32; o; o >>= 1) ss += __shfl_xor(ss, o);
  __shared__ float sred[4];
  if ((threadIdx.x & 63) == 0) sred[threadIdx.x >> 6] = ss;
  __syncthreads();
  float tot = sred[0] + sred[1] + sred[2] + sred[3];
  float sc = rsqrtf(tot * (1.f / Dz) + 1e-6f);
  float4 wv = *(const float4*)(w + c4);
  float o0 = v.x*sc*wv.x, o1 = v.y*sc*wv.y, o2 = v.z*sc*wv.z, o3 = v.w*sc*wv.w;
  size_t ci = (size_t)row * Dz + c4;
  if (HL) {
    split2(o0, oh[ci], ol[ci]);   split2(o1, oh[ci+1], ol[ci+1]);
    split2(o2, oh[ci+2], ol[ci+2]); split2(o3, oh[ci+3], ol[ci+3]);
  } else {
    oh[ci] = f2b(o0); oh[ci+1] = f2b(o1); oh[ci+2] = f2b(o2); oh[ci+3] = f2b(o3);
  }
}

// ======== 128x128 LDS-staged split GEMM body (3-term) ========
// DB=false: single-buffered (32KB LDS — best for in_proj occupancy)
// DB=true : 2-phase double-buffered (64KB LDS — best for other users)
// EPI 1: dual f32 store: col<2048 -> Cf, else Cf2 (inner ld 2048)   (in_proj)
// EPI 3: Cf = v + epi[ci]; EPI 4: Cf += v                           (out_proj)
// EPI 5: Cf[row*ldc+col] = softplus(v + epi[col])                   (dt_proj)
// EPI 6: hi/lo -> C1h/C1l (ldc=128); cols [64,96) also -> Cf[row*32+col-64]  (x_proj)
template<int EPI, bool DB>
__device__ __forceinline__ void sp128_body(
    int row0, int n00,
    const bf16* __restrict__ Ah, const bf16* __restrict__ Al, int lda,
    const bf16* __restrict__ Bh, const bf16* __restrict__ Bl, int ldb,
    bf16* __restrict__ C1h, bf16* __restrict__ C1l,
    float* __restrict__ Cf, float* __restrict__ Cf2, int ldc, int K,
    const float* __restrict__ epi)
{
  constexpr int NB = DB ? 2 : 1;
  __shared__ __align__(16) bf16 sAh[NB][4096], sAl[NB][4096], sBh[NB][4096], sBl[NB][4096];
  int tid = threadIdx.x;
  int lane = tid & 63, w = tid >> 6;
  int wr = (w >> 1) * 64, wc = (w & 1) * 64;
  int srow = w * 32 + (lane >> 2);
  int scol = (((lane & 3) ^ ((lane >> 2) & 3)) * 8);
  const bf16* pAh = Ah + (size_t)(row0 + srow) * lda + scol;
  const bf16* pAl = Al + (size_t)(row0 + srow) * lda + scol;
  const bf16* pBh = Bh + (size_t)(n00 + srow) * ldb + scol;
  const bf16* pBl = Bl + (size_t)(n00 + srow) * ldb + scol;
  int lr = lane & 15;
  int rk = (((lane >> 4) ^ (lane & 3)) * 8);
  f32x4 acc[4][4];
  #pragma unroll
  for (int i = 0; i < 4; ++i)
    #pragma unroll
    for (int j = 0; j < 4; ++j) acc[i][j] = {0.f,0.f,0.f,0.f};
  auto STAGE = [&](int buf, int kt){
    #pragma unroll
    for (int j = 0; j < 2; ++j) {
      int lb = (w * 128 + j * 64) * 8;
      size_t goa = (size_t)j * 16 * lda + kt;
      size_t gob = (size_t)j * 16 * ldb + kt;
      gload16(pAh + goa, &sAh[buf][lb]);
      gload16(pAl + goa, &sAl[buf][lb]);
      gload16(pBh + gob, &sBh[buf][lb]);
      gload16(pBl + gob, &sBl[buf][lb]);
    }
  };
  auto COMPUTE = [&](int buf){
    bf16x8 fa[4], fb[4], ft[4];
    #pragma unroll
    for (int i = 0; i < 4; ++i) {
      fa[i] = *(const bf16x8*)&sAh[buf][(wr + i*16 + lr) * 32 + rk];
      fb[i] = *(const bf16x8*)&sBh[buf][(wc + i*16 + lr) * 32 + rk];
    }
    #pragma unroll
    for (int mi = 0; mi < 4; ++mi)
      #pragma unroll
      for (int ni = 0; ni < 4; ++ni)
        acc[mi][ni] = MFMA(fa[mi], fb[ni], acc[mi][ni]);
    #pragma unroll
    for (int i = 0; i < 4; ++i) ft[i] = *(const bf16x8*)&sBl[buf][(wc + i*16 + lr) * 32 + rk];
    #pragma unroll
    for (int mi = 0; mi < 4; ++mi)
      #pragma unroll
      for (int ni = 0; ni < 4; ++ni)
        acc[mi][ni] = MFMA(fa[mi], ft[ni], acc[mi][ni]);
    #pragma unroll
    for (int i = 0; i < 4; ++i) ft[i] = *(const bf16x8*)&sAl[buf][(wr + i*16 + lr) * 32 + rk];
    #pragma unroll
    for (int mi = 0; mi < 4; ++mi)
      #pragma unroll
      for (int ni = 0; ni < 4; ++ni)
        acc[mi][ni] = MFMA(ft[mi], fb[ni], acc[mi][ni]);
  };
  if (DB) {
    STAGE(0, 0);
    __syncthreads();
    int cur = 0;
    for (int kt = 0; kt < K; kt += 32) {
      if (kt + 32 < K) STAGE(cur ^ 1, kt + 32);
      COMPUTE(cur);
      __syncthreads();
      cur ^= 1;
    }
  } else {
    for (int kt = 0; kt < K; kt += 32) {
      if (kt) __syncthreads();
      STAGE(0, kt);
      __syncthreads();
      COMPUTE(0);
    }
  }
  int crow = (lane >> 4) * 4, ccol = lane & 15;
  #pragma unroll
  for (int mi = 0; mi < 4; ++mi)
  #pragma unroll
  for (int ni = 0; ni < 4; ++ni)
  #pragma unroll
  for (int r = 0; r < 4; ++r) {
    int row = row0 + wr + mi * 16 + crow + r;
    int col = n00 + wc + ni * 16 + ccol;
    float v = acc[mi][ni][r];
    if (EPI == 1) {
      size_t ci = (size_t)row * 2048 + (col & 2047);
      if (col < 2048) Cf[ci] = v; else Cf2[ci] = v;
    } else if (EPI == 3) {
      size_t ci = (size_t)row * ldc + col;
      Cf[ci] = v + epi[ci];
    } else if (EPI == 4) {
      size_t ci = (size_t)row * ldc + col;
      Cf[ci] += v;
    } else if (EPI == 5) {
      float t = v + epi[col];
      Cf[(size_t)row * ldc + col] = (t > 20.f) ? t : log1pf(__expf(t));
    } else if (EPI == 6) {
      size_t ci = (size_t)row * 128 + col;
      split2(v, C1h[ci], C1l[ci]);
      if (col >= 64 && col < 96) Cf[(size_t)row * 32 + col - 64] = v;
    }
  }
}

// ---- named wrappers (plain 2D grids) ----
__global__ __launch_bounds__(256) void k_inproj(
    const bf16* Ah, const bf16* Al, const bf16* Bh, const bf16* Bl,
    float* Cf, float* Cf2){
  sp128_body<1,false>(blockIdx.x*128, blockIdx.y*128, Ah, Al, Dz, Bh, Bl, Dz,
                      nullptr, nullptr, Cf, Cf2, 2048, Dz, nullptr);
}
__global__ __launch_bounds__(256) void k_xproj(
    const bf16* Ah, const bf16* Al, const bf16* Bh, const bf16* Bl,
    bf16* C1h, bf16* C1l, float* Cf){
  sp128_body<6,true>(blockIdx.x*128, blockIdx.y*128, Ah, Al, DIz, Bh, Bl, DIz,
                     C1h, C1l, Cf, nullptr, 128, DIz, nullptr);
}
__global__ __launch_bounds__(256) void k_dtproj(
    const bf16* Ah, const bf16* Al, const bf16* Bh, const bf16* Bl,
    float* Cf, const float* epi){
  sp128_body<5,true>(blockIdx.x*128, blockIdx.y*128, Ah, Al, 128, Bh, Bl, DTRz,
                     nullptr, nullptr, Cf, nullptr, NDH, DTRz, epi);
}
template<int EPI>
__global__ __launch_bounds__(256) void k_outproj(
    const bf16* Ah, const bf16* Al, const bf16* Bh, const bf16* Bl,
    float* Cf, const float* epi){
  sp128_body<EPI,true>(blockIdx.x*128, blockIdx.y*128, Ah, Al, NDH, Bh, Bl, DIz,
                       nullptr, nullptr, Cf, nullptr, Dz, NDH, epi);
}

// ======== 128x128 plain GEMM body, 2-phase double-buffered ========
// EPI 4 = v*wslot[row] (guarded) -> bf16; EPI 5 = f32 +=; EPI 6 = bf16 store
// GATHER: A rows indirected through toks (guarded by counts)
template<int EPI, bool ROUTED, bool GATHER>
__device__ __forceinline__ void gemm128_body(
    int row0, int n00, int e,
    const bf16* __restrict__ A, int lda,
    const bf16* __restrict__ Bm, int ldb,
    void* __restrict__ Cp, int ldc, int K,
    const float* __restrict__ epi,
    const int* __restrict__ offs, const int* __restrict__ toks,
    const int* __restrict__ counts)
{
  __shared__ __align__(16) bf16 sA[2][4096], sB[2][4096];
  int tid = threadIdx.x;
  int lane = tid & 63, w = tid >> 6;
  int wr = (w >> 1) * 64, wc = (w & 1) * 64;
  int srow = w * 32 + (lane >> 2);
  int scol = (((lane & 3) ^ ((lane >> 2) & 3)) * 8);
  size_t arow[2];
  #pragma unroll
  for (int j = 0; j < 2; ++j) {
    int r = row0 + srow + j * 16;
    if (GATHER) {
      int tk = toks[r];
      if (r - offs[e] >= counts[e]) tk = 0;
      tk &= (Tz - 1);
      arow[j] = (size_t)tk * lda;
    } else {
      arow[j] = (size_t)r * lda;
    }
  }
  const bf16* pB = Bm + (size_t)(n00 + srow) * ldb + scol;
  int lr = lane & 15;
  int rk = (((lane >> 4) ^ (lane & 3)) * 8);
  f32x4 acc[4][4];
  #pragma unroll
  for (int i = 0; i < 4; ++i)
    #pragma unroll
    for (int j = 0; j < 4; ++j) acc[i][j] = {0.f,0.f,0.f,0.f};
  auto STAGE = [&](int buf, int kt){
    #pragma unroll
    for (int j = 0; j < 2; ++j) {
      int lb = (w * 128 + j * 64) * 8;
      gload16(A + arow[j] + scol + kt, &sA[buf][lb]);
      gload16(pB + (size_t)j * 16 * ldb + kt, &sB[buf][lb]);
    }
  };
  STAGE(0, 0);
  __syncthreads();
  int cur = 0;
  for (int kt = 0; kt < K; kt += 32) {
    if (kt + 32 < K) STAGE(cur ^ 1, kt + 32);
    bf16x8 fa[4], fb[4];
    #pragma unroll
    for (int i = 0; i < 4; ++i) {
      fa[i] = *(const bf16x8*)&sA[cur][(wr + i*16 + lr) * 32 + rk];
      fb[i] = *(const bf16x8*)&sB[cur][(wc + i*16 + lr) * 32 + rk];
    }
    #pragma unroll
    for (int mi = 0; mi < 4; ++mi)
      #pragma unroll
      for (int ni = 0; ni < 4; ++ni)
        acc[mi][ni] = MFMA(fa[mi], fb[ni], acc[mi][ni]);
    __syncthreads();
    cur ^= 1;
  }
  int crow = (lane >> 4) * 4, ccol = lane & 15;
  int base_e = ROUTED ? offs[e] : 0;
  int cnt_e  = ROUTED ? counts[e] : 0;
  #pragma unroll
  for (int mi = 0; mi < 4; ++mi)
  #pragma unroll
  for (int ni = 0; ni < 4; ++ni)
  #pragma unroll
  for (int r = 0; r < 4; ++r) {
    int row = row0 + wr + mi * 16 + crow + r;
    int col = n00 + wc + ni * 16 + ccol;
    size_t ci = (size_t)row * ldc + col;
    float v = acc[mi][ni][r];
    if (EPI == 4) {
      float wv = (row - base_e < cnt_e) ? epi[row] : 0.f;
      ((bf16*)Cp)[ci] = f2b(v * wv);
    } else if (EPI == 5) ((float*)Cp)[ci] += v;
    else if (EPI == 6) ((bf16*)Cp)[ci] = f2b(v);
  }
}

// expert-tile map helper for routed kernels
__device__ __forceinline__ bool expert_map(const int* offs, int& e, int& row0){
  int bid = blockIdx.x, cum = 0; e = -1; row0 = 0;
  #pragma unroll
  for (int i = 0; i < 8; ++i) {
    int tiles = (offs[i+1] - offs[i]) >> 7;
    if (e < 0 && bid < cum + tiles) { e = i; row0 = offs[i] + ((bid - cum) << 7); }
    cum += tiles;
  }
  return e >= 0;
}

// merged routed GLU GEMM: grid.y 0-7 -> gate (G), 8-15 -> up (U)
__global__ __launch_bounds__(256) void k_moe_glu_r(
    const bf16* A, const bf16* Wg, const bf16* Wu, bf16* G, bf16* U,
    const int* offs, const int* toks, const int* counts){
  int e, row0;
  if (!expert_map(offs, e, row0)) return;
  int by = blockIdx.y;
  const bf16* Bw = (by < 8) ? Wg : Wu;
  bf16* Cp = (by < 8) ? G : U;
  int n00 = (by & 7) * 128;
  gemm128_body<6,true,true>(row0, n00, e, A, Dz, Bw + (size_t)e*Fz*Dz, Dz,
                            Cp, Fz, Dz, nullptr, offs, toks, counts);
}
// merged shared GLU GEMM: grid.y 0-15 -> gate (G), 16-31 -> up (U)
__global__ __launch_bounds__(256) void k_moe_glu_s(
    const bf16* A, const bf16* Wg, const bf16* Wu, bf16* G, bf16* U){
  int by = blockIdx.y;
  const bf16* Bw = (by < 16) ? Wg : Wu;
  bf16* Cp = (by < 16) ? G : U;
  int n00 = (by & 15) * 128;
  gemm128_body<6,false,false>(blockIdx.x*128, n00, 0, A, Dz, Bw, Dz,
                              Cp, FSz, Dz, nullptr, nullptr, nullptr, nullptr);
}
__global__ __launch_bounds__(256) void k_down_routed(
    const bf16* A, const bf16* Bw, bf16* Cp, const float* epi,
    const int* offs, const int* counts){
  int e, row0;
  if (!expert_map(offs, e, row0)) return;
  gemm128_body<4,true,false>(row0, blockIdx.y*128, e, A, Fz, Bw + (size_t)e*Dz*Fz, Fz,
                             Cp, Dz, Fz, epi, offs, nullptr, counts);
}
__global__ __launch_bounds__(256) void k_down_shared(
    const bf16* A, const bf16* Bw, float* Cp){
  gemm128_body<5,false,false>(blockIdx.x*128, blockIdx.y*128, 0, A, FSz, Bw, FSz,
                              Cp, Dz, FSz, nullptr, nullptr, nullptr, nullptr);
}

// ---------------- silu-mul: G = silu(G) * U  (bf16x8 vectorized, in place) ----------------
__global__ __launch_bounds__(256) void k_silumul(bf16* __restrict__ G, const bf16* __restrict__ U){
  long i = ((long)blockIdx.x * 256 + threadIdx.x) * 8;
  bf16x8 gv = *(const bf16x8*)&G[i];
  bf16x8 uv = *(const bf16x8*)&U[i];
  bf16 ov[8];
  #pragma unroll
  for (int k2 = 0; k2 < 8; ++k2) {
    float g = us2f((unsigned short)gv[k2]);
    float u = us2f((unsigned short)uv[k2]);
    ov[k2] = f2b(silu(g) * u);
  }
  *(bf16x8*)&G[i] = *(const bf16x8*)ov;
}

// ---------------- causal depthwise conv (4 taps) + silu; 4 rows per thread ----------------
__global__ __launch_bounds__(256) void k_conv4(const float* __restrict__ xz,
                                               const float* __restrict__ cw, const float* __restrict__ cb,
                                               bf16* __restrict__ oh, bf16* __restrict__ ol){
  int d = blockIdx.x * 256 + threadIdx.x;
  int r0 = blockIdx.y * 4;
  int s0 = r0 & (Sz - 1);
  size_t base = (size_t)r0 * DIz + d;
  float w0 = cw[d*4+0], w1 = cw[d*4+1], w2 = cw[d*4+2], w3 = cw[d*4+3], bb = cb[d];
  float a  = (s0 == 0) ? 0.f : xz[base - 3*DIz];
  float b_ = (s0 == 0) ? 0.f : xz[base - 2*DIz];
  float c  = (s0 == 0) ? 0.f : xz[base - 1*DIz];
  float x0 = xz[base], x1 = xz[base + DIz], x2 = xz[base + 2*DIz], x3 = xz[base + 3*DIz];
  float v0 = bb + w0*a  + w1*b_ + w2*c  + w3*x0;
  float v1 = bb + w0*b_ + w1*c  + w2*x0 + w3*x1;
  float v2 = bb + w0*c  + w1*x0 + w2*x1 + w3*x2;
  float v3 = bb + w0*x0 + w1*x1 + w2*x2 + w3*x3;
  float o0 = v0 / (1.f + __expf(-v0));
  float o1 = v1 / (1.f + __expf(-v1));
  float o2 = v2 / (1.f + __expf(-v2));
  float o3 = v3 / (1.f + __expf(-v3));
  split2(o0, oh[base],         ol[base]);
  split2(o1, oh[base + DIz],   ol[base + DIz]);
  split2(o2, oh[base + 2*DIz], ol[base + 2*DIz]);
  split2(o3, oh[base + 3*DIz], ol[base + 3*DIz]);
}

// ---------------- chunked selective scan: thread-per-d, h[16] in registers ----------------
__global__ __launch_bounds__(256) void k_scan1r(const float* __restrict__ dtf,
                                                const bf16* __restrict__ xih, const bf16* __restrict__ xil,
                                                const float* __restrict__ xdf, const float* __restrict__ A_log,
                                                float* __restrict__ P, float* __restrict__ R){
  int b = blockIdx.y, c = blockIdx.z;
  int d = blockIdx.x * 256 + threadIdx.x;
  __shared__ float sBC[CL2*32];
  int s0 = c * CL2;
  for (int i = threadIdx.x; i < CL2*32; i += 256)
    sBC[i] = xdf[((size_t)b*Sz + s0 + (i >> 5)) * 32 + (i & 31)];
  float Adn[16];
  #pragma unroll
  for (int n = 0; n < 16; ++n) Adn[n] = -__expf(A_log[d*16+n]);
  __syncthreads();
  float h[16];
  #pragma unroll
  for (int n = 0; n < 16; ++n) h[n] = 0.f;
  float sdt = 0.f;
  for (int s = 0; s < CL2; ++s) {
    size_t row = (size_t)b * Sz + s0 + s;
    float dtv = dtf[row * NDH + d];
    float xiv = rc(xih, xil, row * DIz + d);
    float kb = dtv * xiv;
    const float* bc = &sBC[s*32];
    sdt += dtv;
    #pragma unroll
    for (int n = 0; n < 16; ++n) {
      float da = __expf(dtv * Adn[n]);
      h[n] = da * h[n] + kb * bc[n];
    }
  }
  size_t idx = (((size_t)c * Bz + b) * NDH + d) * 16;
  #pragma unroll
  for (int n = 0; n < 16; ++n) { P[idx+n] = __expf(sdt * Adn[n]); R[idx+n] = h[n]; }
}
__global__ __launch_bounds__(256) void k_scan2(const float* __restrict__ P, const float* __restrict__ R,
                                               float* __restrict__ Hin){
  int i = blockIdx.x * 256 + threadIdx.x;
  float h = 0.f;
  #pragma unroll 4
  for (int c = 0; c < NCH2; ++c) {
    size_t idx = (size_t)c * (Bz * NDH * 16) + i;
    Hin[idx] = h;
    h = P[idx] * h + R[idx];
  }
}
__global__ __launch_bounds__(256) void k_scan3r(const float* __restrict__ dtf,
                                                const bf16* __restrict__ xih, const bf16* __restrict__ xil,
                                                const float* __restrict__ xdf, const float* __restrict__ resf,
                                                const float* __restrict__ A_log, const float* __restrict__ Dsk,
                                                const float* __restrict__ Hin,
                                                bf16* __restrict__ yh, bf16* __restrict__ yl){
  int b = blockIdx.y, c = blockIdx.z;
  int d = blockIdx.x * 256 + threadIdx.x;
  __shared__ float sBC[CL2*32];
  int s0 = c * CL2;
  for (int i = threadIdx.x; i < CL2*32; i += 256)
    sBC[i] = xdf[((size_t)b*Sz + s0 + (i >> 5)) * 32 + (i & 31)];
  float Adn[16];
  #pragma unroll
  for (int n = 0; n < 16; ++n) Adn[n] = -__expf(A_log[d*16+n]);
  float Dv = Dsk[d];
  __syncthreads();
  float h[16];
  size_t hidx = (((size_t)c * Bz + b) * NDH + d) * 16;
  #pragma unroll
  for (int n = 0; n < 16; ++n) h[n] = Hin[hidx+n];
  for (int s = 0; s < CL2; ++s) {
    size_t row = (size_t)b * Sz + s0 + s;
    float dtv = dtf[row * NDH + d];
    float xiv = rc(xih, xil, row * DIz + d);
    float kb = dtv * xiv;
    const float* bc = &sBC[s*32];
    float acc = 0.f;
    #pragma unroll
    for (int n = 0; n < 16; ++n) {
      float da = __expf(dtv * Adn[n]);
      h[n] = da * h[n] + kb * bc[n];
      acc = fmaf(h[n], bc[16+n], acc);
    }
    float resv = resf[row * DIz + d];
    float yv = (acc + xiv * Dv) * (resv / (1.f + __expf(-resv)));
    split2(yv, yh[row * NDH + d], yl[row * NDH + d]);
  }
}

// ---------------- MoE gate: 4 tokens/block, NO atomics ----------------
__global__ __launch_bounds__(256) void k_gate(const float* __restrict__ m, const float* __restrict__ nw,
                                              const float* __restrict__ gw, const float* __restrict__ gb,
                                              int* __restrict__ topi, float* __restrict__ topw){
  int t = blockIdx.x * 4 + (threadIdx.x >> 6);
  int lane = threadIdx.x & 63;
  const float* xr = m + (size_t)t * Dz;
  float xv[16];
  float ss = 0.f;
  #pragma unroll
  for (int j = 0; j < 16; ++j) { xv[j] = xr[lane + j * 64]; ss += xv[j] * xv[j]; }
  #pragma unroll
  for (int o = 32; o; o >>= 1) ss += __shfl_xor(ss, o);
  float sc = rsqrtf(ss * (1.f / Dz) + 1e-6f);
  #pragma unroll
  for (int j = 0; j < 16; ++j) xv[j] *= sc * nw[lane + j * 64];
  float acc[8] = {0.f,0.f,0.f,0.f,0.f,0.f,0.f,0.f};
  #pragma unroll
  for (int j = 0; j < 16; ++j) {
    #pragma unroll
    for (int e = 0; e < 8; ++e) acc[e] += xv[j] * gw[e * Dz + lane + j * 64];
  }
  #pragma unroll
  for (int e = 0; e < 8; ++e) {
    float v = acc[e];
    #pragma unroll
    for (int o = 32; o; o >>= 1) v += __shfl_xor(v, o);
    acc[e] = v;
  }
  if (lane == 0) {
    float mx = acc[0];
    #pragma unroll
    for (int e = 1; e < 8; ++e) mx = fmaxf(mx, acc[e]);
    float scr[8]; float sum = 0.f;
    #pragma unroll
    for (int e = 0; e < 8; ++e) { scr[e] = expf(acc[e] - mx); sum += scr[e]; }
    float inv = 1.f / sum;
    #pragma unroll
    for (int e = 0; e < 8; ++e) scr[e] *= inv;
    int i0 = 0; float b0 = -1e30f;
    #pragma unroll
    for (int e = 0; e < 8; ++e) { float kv = scr[e] + gb[e]; if (kv > b0) { b0 = kv; i0 = e; } }
    int i1 = -1; float b1 = -1e30f;
    #pragma unroll
    for (int e = 0; e < 8; ++e) { if (e == i0) continue; float kv = scr[e] + gb[e]; if (kv > b1) { b1 = kv; i1 = e; } }
    float w0 = scr[i0], w1 = scr[i1];
    float wn = 1.f / (w0 + w1 + 1e-9f);
    topi[t*2] = i0; topi[t*2+1] = i1;
    topw[t*2] = w0 * wn; topw[t*2+1] = w1 * wn;
  }
}

// ---------------- expert count: LDS histogram, 8 global atomics per block ----------------
__global__ __launch_bounds__(256) void k_count(const int* __restrict__ topi, int* __restrict__ counts){
  __shared__ int cnt[NE];
  int tid = threadIdx.x;
  if (tid < NE) cnt[tid] = 0;
  __syncthreads();
  int i = blockIdx.x * 256 + tid;
  atomicAdd(&cnt[topi[i]], 1);
  __syncthreads();
  if (tid < NE) atomicAdd(&counts[tid], cnt[tid]);
}

__global__ void k_offs(const int* __restrict__ counts, int* __restrict__ offs, int* __restrict__ fill){
  if (threadIdx.x == 0) {
    int o = 0;
    for (int e = 0; e < 8; ++e) { offs[e] = o; o += ((counts[e] + 127) & ~127); }
    offs[8] = o;
  }
  if (threadIdx.x < 8) fill[threadIdx.x] = 0;
}

// ---------------- scatter: per-block LDS positions + 8 reservation atomics ----------------
__global__ __launch_bounds__(256) void k_scatter(const int* __restrict__ topi, const float* __restrict__ topw,
                                                 const int* __restrict__ offs, int* __restrict__ fill,
                                                 int* __restrict__ toks, float* __restrict__ wslot,
                                                 int* __restrict__ slot_of){
  __shared__ int cnt[NE], basee[NE];
  int tid = threadIdx.x;
  if (tid < NE) cnt[tid] = 0;
  __syncthreads();
  int i = blockIdx.x * 256 + tid;
  int e = topi[i];
  int pos = atomicAdd(&cnt[e], 1);
  __syncthreads();
  if (tid < NE) basee[tid] = atomicAdd(&fill[tid], cnt[tid]);
  __syncthreads();
  int slot = offs[e] + basee[e] + pos;
  toks[slot] = i >> 1;
  wslot[slot] = topw[i];
  slot_of[i] = slot;
}

// ---------------- final combine: out = m + down0 + down1 ----------------
__global__ __launch_bounds__(256) void k_combine(const float* __restrict__ m,
                                                 const bf16* __restrict__ Hd, const int* __restrict__ slot_of,
                                                 float* __restrict__ out){
  int t = blockIdx.x;
  int ci = threadIdx.x * 4;
  int s0 = slot_of[t*2], s1 = slot_of[t*2+1];
  size_t base = (size_t)t * Dz + ci;
  float4 mv = *(const float4*)(m + base);
  ushort4 h0 = *(const ushort4*)((const unsigned short*)Hd + (size_t)s0 * Dz + ci);
  ushort4 h1 = *(const ushort4*)((const unsigned short*)Hd + (size_t)s1 * Dz + ci);
  out[base+0] = mv.x + us2f(h0.x) + us2f(h1.x);
  out[base+1] = mv.y + us2f(h0.y) + us2f(h1.y);
  out[base+2] = mv.z + us2f(h0.z) + us2f(h1.z);
  out[base+3] = mv.w + us2f(h0.w) + us2f(h1.w);
}

extern "C" void kernel_launch(void* const* d_in, const int* in_sizes, int n_in,
                              void* d_out, int out_size, void* d_ws, size_t ws_size,
                              hipStream_t stream) {
  (void)in_sizes; (void)n_in; (void)out_size;
  const float* x         = (const float*)d_in[0];
  const float* norm_w    = (const float*)d_in[1];
  const float* in_proj   = (const float*)d_in[2];
  const float* conv_w    = (const float*)d_in[3];
  const float* conv_b    = (const float*)d_in[4];
  const float* x_proj    = (const float*)d_in[5];
  const float* dt_proj   = (const float*)d_in[6];
  const float* dt_proj_b = (const float*)d_in[7];
  const float* A_log     = (const float*)d_in[8];
  const float* D_skip    = (const float*)d_in[9];
  const float* out_proj  = (const float*)d_in[10];
  const float* gate_w    = (const float*)d_in[11];
  const float* gate_b    = (const float*)d_in[12];
  const float* w_gate    = (const float*)d_in[13];
  const float* w_up      = (const float*)d_in[14];
  const float* w_down    = (const float*)d_in[15];
  const float* ws_gate   = (const float*)d_in[16];
  const float* ws_up     = (const float*)d_in[17];
  const float* ws_down   = (const float*)d_in[18];
  float* out = (float*)d_out;

  const size_t MB = 1024 * 1024;
  const size_t NEED = 253 * MB;
  if (ws_size < NEED) {
    k_fill<<<dim3(1), dim3(256), 0, stream>>>(out, (float)(ws_size / MB));
    fprintf(stderr, "kernel_launch: ws_size=%zu < needed=%zu\n", ws_size, NEED);
    return;
  }
  char* P = (char*)d_ws;
  // ---- phase A layout ----
  float* res_f = (float*)(P + 0*MB);
  bf16*  xi_h  = (bf16*)(P + 64*MB);
  bf16*  xi_l  = (bf16*)(P + 96*MB);
  bf16*  xd_h  = (bf16*)(P + 128*MB);
  bf16*  xd_l  = (bf16*)(P + 130*MB);
  float* xdf   = (float*)(P + 132*MB);
  bf16*  xph   = (bf16*)(P + 133*MB);
  bf16*  xpl   = (bf16*)(P + 133*MB + 512*1024);
  bf16*  dph   = (bf16*)(P + 134*MB);
  bf16*  dpl   = (bf16*)(P + 134*MB + 256*1024);
  bf16*  oph   = (bf16*)(P + 135*MB);
  bf16*  opl   = (bf16*)(P + 139*MB);
  float* dtf   = (float*)(P + 144*MB);
  float* scanH = (float*)(P + 176*MB);
  bf16*  y_h   = (bf16*)(P + 188*MB);
  float* scanP = (float*)(P + 192*MB);
  float* scanR = (float*)(P + 200*MB);
  bf16*  y_l   = (bf16*)(P + 204*MB);
  float* mbuf  = (float*)(P + 220*MB);
  // transients:
  bf16*  nrm_h = (bf16*)(P + 144*MB);
  bf16*  nrm_l = (bf16*)(P + 160*MB);
  bf16*  iph   = (bf16*)(P + 176*MB);
  bf16*  ipl   = (bf16*)(P + 184*MB);
  float* xzi_f = (float*)(P + 192*MB);
  // ---- phase B (MoE) overlay ----
  bf16* n2b   = (bf16*)(P + 0*MB);
  bf16* wgh   = (bf16*)(P + 16*MB);
  bf16* wuh   = (bf16*)(P + 32*MB);
  bf16* wdh   = (bf16*)(P + 48*MB);
  bf16* wsg   = (bf16*)(P + 64*MB);
  bf16* wsu   = (bf16*)(P + 68*MB);
  bf16* wsd   = (bf16*)(P + 72*MB);
  bf16* Hbuf  = (bf16*)(P + 76*MB);    // G (routed) then H after silumul; 34MB
  bf16* Hd    = (bf16*)(P + 110*MB);   // 34MB
  bf16* Sh    = (bf16*)(P + 144*MB);   // G (shared) then H; 32MB
  bf16* Utmp  = (bf16*)(P + 176*MB);   // 34MB (over dead scan/y region)
  char* Rt    = P + 252*MB;
  int*   counts  = (int*)(Rt);
  int*   offsb   = (int*)(Rt + 64);
  int*   fill    = (int*)(Rt + 128);
  int*   topi    = (int*)(Rt + 1024);
  float* topw    = (float*)(Rt + 1024 + 65536);
  int*   toks    = (int*)(Rt + 1024 + 2*65536);
  float* wslot   = (float*)(Rt + 1024 + 2*65536 + 69632);
  int*   slot_of = (int*)(Rt + 1024 + 2*65536 + 2*69632);

  // fused mamba weight splits + x_proj pad
  k_split3<<<dim3(6272), dim3(256), 0, stream>>>(in_proj, iph, ipl, out_proj, oph, opl, dt_proj, dph, dpl);
  k_split_pad<<<dim3(256), dim3(256), 0, stream>>>(x_proj, xph, xpl);

  // 1. rmsnorm(x) -> normed hi/lo
  k_rmsnorm<true><<<dim3(Tz), dim3(256), 0, stream>>>(x, norm_w, nrm_h, nrm_l);
  // 2. in_proj: dual f32 store -> xzi_f / res_f (single merged dispatch, best measured)
  k_inproj<<<dim3(Tz/128, 4096/128), dim3(256), 0, stream>>>(nrm_h, nrm_l, iph, ipl, xzi_f, res_f);
  // 3. causal conv + silu -> xi hi/lo
  k_conv4<<<dim3(DIz/256, Tz/4), dim3(256), 0, stream>>>(xzi_f, conv_w, conv_b, xi_h, xi_l);
  // 4. x_proj -> xd hi/lo + xdf f32 (B|C)
  k_xproj<<<dim3(Tz/128, 1), dim3(256), 0, stream>>>(xi_h, xi_l, xph, xpl, xd_h, xd_l, xdf);

  // 5-7. per d-half: dt_proj -> scan -> out_proj partial
  for (int h = 0; h < 2; ++h) {
    int d0 = h * NDH;
    k_dtproj<<<dim3(Tz/128, NDH/128), dim3(256), 0, stream>>>(
        xd_h, xd_l, dph + (size_t)d0*DTRz, dpl + (size_t)d0*DTRz, dtf, dt_proj_b + d0);
    k_scan1r<<<dim3(NDH/256, Bz, NCH2), dim3(256), 0, stream>>>(
        dtf, xi_h + d0, xi_l + d0, xdf, A_log + (size_t)d0*DSz, scanP, scanR);
    k_scan2<<<dim3(Bz*NDH*DSz/256), dim3(256), 0, stream>>>(scanP, scanR, scanH);
    k_scan3r<<<dim3(NDH/256, Bz, NCH2), dim3(256), 0, stream>>>(
        dtf, xi_h + d0, xi_l + d0, xdf, res_f + d0, A_log + (size_t)d0*DSz,
        D_skip + d0, scanH, y_h, y_l);
    if (h == 0)
      k_outproj<3><<<dim3(Tz/128, Dz/128), dim3(256), 0, stream>>>(
          y_h, y_l, oph + d0, opl + d0, mbuf, x);
    else
      k_outproj<4><<<dim3(Tz/128, Dz/128), dim3(256), 0, stream>>>(
          y_h, y_l, oph + d0, opl + d0, mbuf, nullptr);
  }

  // MoE weight conversion
  k_f2bf6<<<dim3(30720), dim3(256), 0, stream>>>(
      w_gate, wgh, w_up, wuh, w_down, wdh, ws_gate, wsg, ws_up, wsu, ws_down, wsd);
  // 8. rmsnorm(m) -> n2 bf16
  k_rmsnorm<false><<<dim3(Tz), dim3(256), 0, stream>>>(mbuf, norm_w, n2b, nullptr);
  // 9. gate (no atomics) + count + routing
  k_gate<<<dim3(Tz/4), dim3(256), 0, stream>>>(mbuf, norm_w, gate_w, gate_b, topi, topw);
  k_zero_counts<<<dim3(1), dim3(64), 0, stream>>>(counts);
  k_count<<<dim3(Tz*2/256), dim3(256), 0, stream>>>(topi, counts);
  k_offs<<<dim3(1), dim3(64), 0, stream>>>(counts, offsb, fill);
  k_scatter<<<dim3(Tz*2/256), dim3(256), 0, stream>>>(topi, topw, offsb, fill, toks, wslot, slot_of);
  // 10. routed experts: merged gate|up GEMM, silumul, down
  k_moe_glu_r<<<dim3(SLOTCAP/128, 16), dim3(256), 0, stream>>>(
      n2b, wgh, wuh, Hbuf, Utmp, offsb, toks, counts);
  k_silumul<<<dim3((unsigned)((size_t)SLOTCAP*Fz/2048)), dim3(256), 0, stream>>>(Hbuf, Utmp);
  k_down_routed<<<dim3(SLOTCAP/128, Dz/128), dim3(256), 0, stream>>>(
      Hbuf, wdh, Hd, wslot, offsb, counts);
  // 11. shared expert: merged gate|up GEMM, silumul
  k_moe_glu_s<<<dim3(Tz/128, 32), dim3(256), 0, stream>>>(n2b, wsg, wsu, Sh, Utmp);
  k_silumul<<<dim3((unsigned)((size_t)Tz*FSz/2048)), dim3(256), 0, stream>>>(Sh, Utmp);
  // 12. combine -> out = m + routed
  k_combine<<<dim3(Tz), dim3(256), 0, stream>>>(mbuf, Hd, slot_of, out);
  // 13. shared down: out += Sh @ ws_down^T
  k_down_shared<<<dim3(Tz/128, Dz/128), dim3(256), 0, stream>>>(Sh, wsd, out);
}

// Round 20
// 1197.762 us; speedup vs baseline: 1.0315x; 1.0002x over previous
//
#include <hip/hip_runtime.h>
#include <hip/hip_bf16.h>
#include <cstdio>

#define Bz 2
#define Sz 4096
#define Dz 1024
#define DIz 2048
#define DSz 16
#define DTRz 64
#define NE 8
#define Fz 1024
#define FSz 2048
#define Tz (Bz*Sz)            // 8192 tokens
#define NDH 1024              // d-half width
#define NCH2 64
#define CL2 (Sz/NCH2)         // 64
#define SLOTCAP 17408         // 136 tiles * 128

typedef __hip_bfloat16 bf16;
typedef short bf16x8 __attribute__((ext_vector_type(8)));
typedef float f32x4 __attribute__((ext_vector_type(4)));

#define MFMA(a,b,c) __builtin_amdgcn_mfma_f32_16x16x32_bf16(a,b,c,0,0,0)

__device__ __forceinline__ float b2f(bf16 v){ return __bfloat162float(v); }
__device__ __forceinline__ bf16  f2b(float v){ return __float2bfloat16(v); }
__device__ __forceinline__ float us2f(unsigned short u){
  union { unsigned int i; float f; } v; v.i = ((unsigned int)u) << 16; return v.f;
}
__device__ __forceinline__ float silu(float v){ return v / (1.f + __expf(-v)); }
__device__ __forceinline__ void split2(float v, bf16& h, bf16& l){ h = f2b(v); l = f2b(v - b2f(h)); }
__device__ __forceinline__ float rc(const bf16* __restrict__ h, const bf16* __restrict__ l, size_t i){
  return b2f(h[i]) + b2f(l[i]);
}
__device__ __forceinline__ void gload16(const bf16* g, bf16* l){
  __builtin_amdgcn_global_load_lds(
      (const __attribute__((address_space(1))) void*)g,
      (__attribute__((address_space(3))) void*)l, 16, 0, 0);
}

// ---------------- guard diagnostic ----------------
__global__ void k_fill(float* __restrict__ o, float v){ o[threadIdx.x] = v; }

// ---------------- fused weight conversions ----------------
__global__ __launch_bounds__(256) void k_split3(
    const float* __restrict__ s0, bf16* __restrict__ h0, bf16* __restrict__ l0,
    const float* __restrict__ s1, bf16* __restrict__ h1, bf16* __restrict__ l1,
    const float* __restrict__ s2, bf16* __restrict__ h2, bf16* __restrict__ l2){
  long i = ((long)blockIdx.x * 256 + threadIdx.x) * 4;
  const float* s; bf16 *dh, *dl; long off;
  if (i < 4194304L)            { s = s0; dh = h0; dl = l0; off = i; }
  else if (i < 6291456L)       { s = s1; dh = h1; dl = l1; off = i - 4194304L; }
  else                          { s = s2; dh = h2; dl = l2; off = i - 6291456L; }
  float4 v = *(const float4*)(s + off);
  split2(v.x, dh[off],   dl[off]);
  split2(v.y, dh[off+1], dl[off+1]);
  split2(v.z, dh[off+2], dl[off+2]);
  split2(v.w, dh[off+3], dl[off+3]);
}
__global__ __launch_bounds__(256) void k_f2bf6(
    const float* __restrict__ s0, bf16* __restrict__ d0,
    const float* __restrict__ s1, bf16* __restrict__ d1,
    const float* __restrict__ s2, bf16* __restrict__ d2,
    const float* __restrict__ s3, bf16* __restrict__ d3,
    const float* __restrict__ s4, bf16* __restrict__ d4,
    const float* __restrict__ s5, bf16* __restrict__ d5){
  long i = ((long)blockIdx.x * 256 + threadIdx.x) * 4;
  const float* s; bf16* d; long off;
  if (i < 8388608L)        { s = s0; d = d0; off = i; }
  else if (i < 16777216L)  { s = s1; d = d1; off = i - 8388608L; }
  else if (i < 25165824L)  { s = s2; d = d2; off = i - 16777216L; }
  else if (i < 27262976L)  { s = s3; d = d3; off = i - 25165824L; }
  else if (i < 29360128L)  { s = s4; d = d4; off = i - 27262976L; }
  else                      { s = s5; d = d5; off = i - 29360128L; }
  float4 v = *(const float4*)(s + off);
  d[off] = f2b(v.x); d[off+1] = f2b(v.y); d[off+2] = f2b(v.z); d[off+3] = f2b(v.w);
}
__global__ __launch_bounds__(256) void k_split_pad(const float* __restrict__ s, bf16* __restrict__ dh,
                                                   bf16* __restrict__ dl){
  int i = (blockIdx.x * 256 + threadIdx.x) * 4;
  int row = i >> 11;
  if (row < 96) {
    float4 v = *(const float4*)(s + i);
    split2(v.x, dh[i],   dl[i]);
    split2(v.y, dh[i+1], dl[i+1]);
    split2(v.z, dh[i+2], dl[i+2]);
    split2(v.w, dh[i+3], dl[i+3]);
  } else {
    bf16 z = f2b(0.f);
    dh[i]=z; dh[i+1]=z; dh[i+2]=z; dh[i+3]=z;
    dl[i]=z; dl[i+1]=z; dl[i+2]=z; dl[i+3]=z;
  }
}

__global__ void k_zero_counts(int* __restrict__ c){
  if (threadIdx.x < NE) c[threadIdx.x] = 0;
}

// ---------------- rmsnorm ----------------
template<bool HL>
__global__ __launch_bounds__(256) void k_rmsnorm(const float* __restrict__ x, const float* __restrict__ w,
                                                 bf16* __restrict__ oh, bf16* __restrict__ ol){
  int row = blockIdx.x;
  const float* xr = x + (size_t)row * Dz;
  int c4 = threadIdx.x * 4;
  float4 v = *(const float4*)(xr + c4);
  float ss = v.x*v.x + v.y*v.y + v.z*v.z + v.w*v.w;
  #pragma unroll
  for (int o = 32; o; o >>= 1) ss += __shfl_xor(ss, o);
  __shared__ float sred[4];
  if ((threadIdx.x & 63) == 0) sred[threadIdx.x >> 6] = ss;
  __syncthreads();
  float tot = sred[0] + sred[1] + sred[2] + sred[3];
  float sc = rsqrtf(tot * (1.f / Dz) + 1e-6f);
  float4 wv = *(const float4*)(w + c4);
  float o0 = v.x*sc*wv.x, o1 = v.y*sc*wv.y, o2 = v.z*sc*wv.z, o3 = v.w*sc*wv.w;
  size_t ci = (size_t)row * Dz + c4;
  if (HL) {
    split2(o0, oh[ci], ol[ci]);   split2(o1, oh[ci+1], ol[ci+1]);
    split2(o2, oh[ci+2], ol[ci+2]); split2(o3, oh[ci+3], ol[ci+3]);
  } else {
    oh[ci] = f2b(o0); oh[ci+1] = f2b(o1); oh[ci+2] = f2b(o2); oh[ci+3] = f2b(o3);
  }
}

// ======== 128x128 LDS-staged split GEMM body (3-term) ========
// DB=false: single-buffered (32KB LDS — best for in_proj occupancy)
// DB=true : 2-phase double-buffered (64KB LDS — best for other users)
// EPI 1: dual f32 store: col<2048 -> Cf, else Cf2 (inner ld 2048)   (in_proj)
// EPI 3: Cf = v + epi[ci]; EPI 4: Cf += v                           (out_proj)
// EPI 5: Cf[row*ldc+col] = softplus(v + epi[col])                   (dt_proj)
// EPI 6: hi/lo -> C1h/C1l (ldc=128); cols [64,96) also -> Cf[row*32+col-64]  (x_proj)
template<int EPI, bool DB>
__device__ __forceinline__ void sp128_body(
    int row0, int n00,
    const bf16* __restrict__ Ah, const bf16* __restrict__ Al, int lda,
    const bf16* __restrict__ Bh, const bf16* __restrict__ Bl, int ldb,
    bf16* __restrict__ C1h, bf16* __restrict__ C1l,
    float* __restrict__ Cf, float* __restrict__ Cf2, int ldc, int K,
    const float* __restrict__ epi)
{
  constexpr int NB = DB ? 2 : 1;
  __shared__ __align__(16) bf16 sAh[NB][4096], sAl[NB][4096], sBh[NB][4096], sBl[NB][4096];
  int tid = threadIdx.x;
  int lane = tid & 63, w = tid >> 6;
  int wr = (w >> 1) * 64, wc = (w & 1) * 64;
  int srow = w * 32 + (lane >> 2);
  int scol = (((lane & 3) ^ ((lane >> 2) & 3)) * 8);
  const bf16* pAh = Ah + (size_t)(row0 + srow) * lda + scol;
  const bf16* pAl = Al + (size_t)(row0 + srow) * lda + scol;
  const bf16* pBh = Bh + (size_t)(n00 + srow) * ldb + scol;
  const bf16* pBl = Bl + (size_t)(n00 + srow) * ldb + scol;
  int lr = lane & 15;
  int rk = (((lane >> 4) ^ (lane & 3)) * 8);
  f32x4 acc[4][4];
  #pragma unroll
  for (int i = 0; i < 4; ++i)
    #pragma unroll
    for (int j = 0; j < 4; ++j) acc[i][j] = {0.f,0.f,0.f,0.f};
  auto STAGE = [&](int buf, int kt){
    #pragma unroll
    for (int j = 0; j < 2; ++j) {
      int lb = (w * 128 + j * 64) * 8;
      size_t goa = (size_t)j * 16 * lda + kt;
      size_t gob = (size_t)j * 16 * ldb + kt;
      gload16(pAh + goa, &sAh[buf][lb]);
      gload16(pAl + goa, &sAl[buf][lb]);
      gload16(pBh + gob, &sBh[buf][lb]);
      gload16(pBl + gob, &sBl[buf][lb]);
    }
  };
  auto COMPUTE = [&](int buf){
    bf16x8 fa[4], fb[4], ft[4];
    #pragma unroll
    for (int i = 0; i < 4; ++i) {
      fa[i] = *(const bf16x8*)&sAh[buf][(wr + i*16 + lr) * 32 + rk];
      fb[i] = *(const bf16x8*)&sBh[buf][(wc + i*16 + lr) * 32 + rk];
    }
    #pragma unroll
    for (int mi = 0; mi < 4; ++mi)
      #pragma unroll
      for (int ni = 0; ni < 4; ++ni)
        acc[mi][ni] = MFMA(fa[mi], fb[ni], acc[mi][ni]);
    #pragma unroll
    for (int i = 0; i < 4; ++i) ft[i] = *(const bf16x8*)&sBl[buf][(wc + i*16 + lr) * 32 + rk];
    #pragma unroll
    for (int mi = 0; mi < 4; ++mi)
      #pragma unroll
      for (int ni = 0; ni < 4; ++ni)
        acc[mi][ni] = MFMA(fa[mi], ft[ni], acc[mi][ni]);
    #pragma unroll
    for (int i = 0; i < 4; ++i) ft[i] = *(const bf16x8*)&sAl[buf][(wr + i*16 + lr) * 32 + rk];
    #pragma unroll
    for (int mi = 0; mi < 4; ++mi)
      #pragma unroll
      for (int ni = 0; ni < 4; ++ni)
        acc[mi][ni] = MFMA(ft[mi], fb[ni], acc[mi][ni]);
  };
  if (DB) {
    STAGE(0, 0);
    __syncthreads();
    int cur = 0;
    for (int kt = 0; kt < K; kt += 32) {
      if (kt + 32 < K) STAGE(cur ^ 1, kt + 32);
      COMPUTE(cur);
      __syncthreads();
      cur ^= 1;
    }
  } else {
    for (int kt = 0; kt < K; kt += 32) {
      if (kt) __syncthreads();
      STAGE(0, kt);
      __syncthreads();
      COMPUTE(0);
    }
  }
  int crow = (lane >> 4) * 4, ccol = lane & 15;
  #pragma unroll
  for (int mi = 0; mi < 4; ++mi)
  #pragma unroll
  for (int ni = 0; ni < 4; ++ni)
  #pragma unroll
  for (int r = 0; r < 4; ++r) {
    int row = row0 + wr + mi * 16 + crow + r;
    int col = n00 + wc + ni * 16 + ccol;
    float v = acc[mi][ni][r];
    if (EPI == 1) {
      size_t ci = (size_t)row * 2048 + (col & 2047);
      if (col < 2048) Cf[ci] = v; else Cf2[ci] = v;
    } else if (EPI == 3) {
      size_t ci = (size_t)row * ldc + col;
      Cf[ci] = v + epi[ci];
    } else if (EPI == 4) {
      size_t ci = (size_t)row * ldc + col;
      Cf[ci] += v;
    } else if (EPI == 5) {
      float t = v + epi[col];
      Cf[(size_t)row * ldc + col] = (t > 20.f) ? t : log1pf(__expf(t));
    } else if (EPI == 6) {
      size_t ci = (size_t)row * 128 + col;
      split2(v, C1h[ci], C1l[ci]);
      if (col >= 64 && col < 96) Cf[(size_t)row * 32 + col - 64] = v;
    }
  }
}

// ---- named wrappers (plain 2D grids) ----
__global__ __launch_bounds__(256) void k_inproj(
    const bf16* Ah, const bf16* Al, const bf16* Bh, const bf16* Bl,
    float* Cf, float* Cf2){
  sp128_body<1,false>(blockIdx.x*128, blockIdx.y*128, Ah, Al, Dz, Bh, Bl, Dz,
                      nullptr, nullptr, Cf, Cf2, 2048, Dz, nullptr);
}
__global__ __launch_bounds__(256) void k_xproj(
    const bf16* Ah, const bf16* Al, const bf16* Bh, const bf16* Bl,
    bf16* C1h, bf16* C1l, float* Cf){
  sp128_body<6,true>(blockIdx.x*128, blockIdx.y*128, Ah, Al, DIz, Bh, Bl, DIz,
                     C1h, C1l, Cf, nullptr, 128, DIz, nullptr);
}
__global__ __launch_bounds__(256) void k_dtproj(
    const bf16* Ah, const bf16* Al, const bf16* Bh, const bf16* Bl,
    float* Cf, const float* epi){
  sp128_body<5,true>(blockIdx.x*128, blockIdx.y*128, Ah, Al, 128, Bh, Bl, DTRz,
                     nullptr, nullptr, Cf, nullptr, NDH, DTRz, epi);
}
template<int EPI>
__global__ __launch_bounds__(256) void k_outproj(
    const bf16* Ah, const bf16* Al, const bf16* Bh, const bf16* Bl,
    float* Cf, const float* epi){
  sp128_body<EPI,true>(blockIdx.x*128, blockIdx.y*128, Ah, Al, NDH, Bh, Bl, DIz,
                       nullptr, nullptr, Cf, nullptr, Dz, NDH, epi);
}

// ======== 128x128 plain GEMM body, 2-phase double-buffered ========
// EPI 4 = v*wslot[row] (guarded) -> bf16; EPI 5 = f32 +=; EPI 6 = bf16 store
// GATHER: A rows indirected through toks (guarded by counts)
template<int EPI, bool ROUTED, bool GATHER>
__device__ __forceinline__ void gemm128_body(
    int row0, int n00, int e,
    const bf16* __restrict__ A, int lda,
    const bf16* __restrict__ Bm, int ldb,
    void* __restrict__ Cp, int ldc, int K,
    const float* __restrict__ epi,
    const int* __restrict__ offs, const int* __restrict__ toks,
    const int* __restrict__ counts)
{
  __shared__ __align__(16) bf16 sA[2][4096], sB[2][4096];
  int tid = threadIdx.x;
  int lane = tid & 63, w = tid >> 6;
  int wr = (w >> 1) * 64, wc = (w & 1) * 64;
  int srow = w * 32 + (lane >> 2);
  int scol = (((lane & 3) ^ ((lane >> 2) & 3)) * 8);
  size_t arow[2];
  #pragma unroll
  for (int j = 0; j < 2; ++j) {
    int r = row0 + srow + j * 16;
    if (GATHER) {
      int tk = toks[r];
      if (r - offs[e] >= counts[e]) tk = 0;
      tk &= (Tz - 1);
      arow[j] = (size_t)tk * lda;
    } else {
      arow[j] = (size_t)r * lda;
    }
  }
  const bf16* pB = Bm + (size_t)(n00 + srow) * ldb + scol;
  int lr = lane & 15;
  int rk = (((lane >> 4) ^ (lane & 3)) * 8);
  f32x4 acc[4][4];
  #pragma unroll
  for (int i = 0; i < 4; ++i)
    #pragma unroll
    for (int j = 0; j < 4; ++j) acc[i][j] = {0.f,0.f,0.f,0.f};
  auto STAGE = [&](int buf, int kt){
    #pragma unroll
    for (int j = 0; j < 2; ++j) {
      int lb = (w * 128 + j * 64) * 8;
      gload16(A + arow[j] + scol + kt, &sA[buf][lb]);
      gload16(pB + (size_t)j * 16 * ldb + kt, &sB[buf][lb]);
    }
  };
  STAGE(0, 0);
  __syncthreads();
  int cur = 0;
  for (int kt = 0; kt < K; kt += 32) {
    if (kt + 32 < K) STAGE(cur ^ 1, kt + 32);
    bf16x8 fa[4], fb[4];
    #pragma unroll
    for (int i = 0; i < 4; ++i) {
      fa[i] = *(const bf16x8*)&sA[cur][(wr + i*16 + lr) * 32 + rk];
      fb[i] = *(const bf16x8*)&sB[cur][(wc + i*16 + lr) * 32 + rk];
    }
    #pragma unroll
    for (int mi = 0; mi < 4; ++mi)
      #pragma unroll
      for (int ni = 0; ni < 4; ++ni)
        acc[mi][ni] = MFMA(fa[mi], fb[ni], acc[mi][ni]);
    __syncthreads();
    cur ^= 1;
  }
  int crow = (lane >> 4) * 4, ccol = lane & 15;
  int base_e = ROUTED ? offs[e] : 0;
  int cnt_e  = ROUTED ? counts[e] : 0;
  #pragma unroll
  for (int mi = 0; mi < 4; ++mi)
  #pragma unroll
  for (int ni = 0; ni < 4; ++ni)
  #pragma unroll
  for (int r = 0; r < 4; ++r) {
    int row = row0 + wr + mi * 16 + crow + r;
    int col = n00 + wc + ni * 16 + ccol;
    size_t ci = (size_t)row * ldc + col;
    float v = acc[mi][ni][r];
    if (EPI == 4) {
      float wv = (row - base_e < cnt_e) ? epi[row] : 0.f;
      ((bf16*)Cp)[ci] = f2b(v * wv);
    } else if (EPI == 5) ((float*)Cp)[ci] += v;
    else if (EPI == 6) ((bf16*)Cp)[ci] = f2b(v);
  }
}

// expert-tile map helper for routed kernels
__device__ __forceinline__ bool expert_map(const int* offs, int& e, int& row0){
  int bid = blockIdx.x, cum = 0; e = -1; row0 = 0;
  #pragma unroll
  for (int i = 0; i < 8; ++i) {
    int tiles = (offs[i+1] - offs[i]) >> 7;
    if (e < 0 && bid < cum + tiles) { e = i; row0 = offs[i] + ((bid - cum) << 7); }
    cum += tiles;
  }
  return e >= 0;
}

// merged routed GLU GEMM: grid.y 0-7 -> gate (G), 8-15 -> up (U)
__global__ __launch_bounds__(256) void k_moe_glu_r(
    const bf16* A, const bf16* Wg, const bf16* Wu, bf16* G, bf16* U,
    const int* offs, const int* toks, const int* counts){
  int e, row0;
  if (!expert_map(offs, e, row0)) return;
  int by = blockIdx.y;
  const bf16* Bw = (by < 8) ? Wg : Wu;
  bf16* Cp = (by < 8) ? G : U;
  int n00 = (by & 7) * 128;
  gemm128_body<6,true,true>(row0, n00, e, A, Dz, Bw + (size_t)e*Fz*Dz, Dz,
                            Cp, Fz, Dz, nullptr, offs, toks, counts);
}
// merged shared GLU GEMM: grid.y 0-15 -> gate (G), 16-31 -> up (U)
__global__ __launch_bounds__(256) void k_moe_glu_s(
    const bf16* A, const bf16* Wg, const bf16* Wu, bf16* G, bf16* U){
  int by = blockIdx.y;
  const bf16* Bw = (by < 16) ? Wg : Wu;
  bf16* Cp = (by < 16) ? G : U;
  int n00 = (by & 15) * 128;
  gemm128_body<6,false,false>(blockIdx.x*128, n00, 0, A, Dz, Bw, Dz,
                              Cp, FSz, Dz, nullptr, nullptr, nullptr, nullptr);
}
__global__ __launch_bounds__(256) void k_down_routed(
    const bf16* A, const bf16* Bw, bf16* Cp, const float* epi,
    const int* offs, const int* counts){
  int e, row0;
  if (!expert_map(offs, e, row0)) return;
  gemm128_body<4,true,false>(row0, blockIdx.y*128, e, A, Fz, Bw + (size_t)e*Dz*Fz, Fz,
                             Cp, Dz, Fz, epi, offs, nullptr, counts);
}
__global__ __launch_bounds__(256) void k_down_shared(
    const bf16* A, const bf16* Bw, float* Cp){
  gemm128_body<5,false,false>(blockIdx.x*128, blockIdx.y*128, 0, A, FSz, Bw, FSz,
                              Cp, Dz, FSz, nullptr, nullptr, nullptr, nullptr);
}

// ---------------- silu-mul: G = silu(G) * U  (bf16x8 vectorized, in place) ----------------
__global__ __launch_bounds__(256) void k_silumul(bf16* __restrict__ G, const bf16* __restrict__ U){
  long i = ((long)blockIdx.x * 256 + threadIdx.x) * 8;
  bf16x8 gv = *(const bf16x8*)&G[i];
  bf16x8 uv = *(const bf16x8*)&U[i];
  bf16 ov[8];
  #pragma unroll
  for (int k2 = 0; k2 < 8; ++k2) {
    float g = us2f((unsigned short)gv[k2]);
    float u = us2f((unsigned short)uv[k2]);
    ov[k2] = f2b(silu(g) * u);
  }
  *(bf16x8*)&G[i] = *(const bf16x8*)ov;
}

// ---------------- causal depthwise conv (4 taps) + silu; 4 rows per thread ----------------
__global__ __launch_bounds__(256) void k_conv4(const float* __restrict__ xz,
                                               const float* __restrict__ cw, const float* __restrict__ cb,
                                               bf16* __restrict__ oh, bf16* __restrict__ ol){
  int d = blockIdx.x * 256 + threadIdx.x;
  int r0 = blockIdx.y * 4;
  int s0 = r0 & (Sz - 1);
  size_t base = (size_t)r0 * DIz + d;
  float w0 = cw[d*4+0], w1 = cw[d*4+1], w2 = cw[d*4+2], w3 = cw[d*4+3], bb = cb[d];
  float a  = (s0 == 0) ? 0.f : xz[base - 3*DIz];
  float b_ = (s0 == 0) ? 0.f : xz[base - 2*DIz];
  float c  = (s0 == 0) ? 0.f : xz[base - 1*DIz];
  float x0 = xz[base], x1 = xz[base + DIz], x2 = xz[base + 2*DIz], x3 = xz[base + 3*DIz];
  float v0 = bb + w0*a  + w1*b_ + w2*c  + w3*x0;
  float v1 = bb + w0*b_ + w1*c  + w2*x0 + w3*x1;
  float v2 = bb + w0*c  + w1*x0 + w2*x1 + w3*x2;
  float v3 = bb + w0*x0 + w1*x1 + w2*x2 + w3*x3;
  float o0 = v0 / (1.f + __expf(-v0));
  float o1 = v1 / (1.f + __expf(-v1));
  float o2 = v2 / (1.f + __expf(-v2));
  float o3 = v3 / (1.f + __expf(-v3));
  split2(o0, oh[base],         ol[base]);
  split2(o1, oh[base + DIz],   ol[base + DIz]);
  split2(o2, oh[base + 2*DIz], ol[base + 2*DIz]);
  split2(o3, oh[base + 3*DIz], ol[base + 3*DIz]);
}

// ---------------- chunked selective scan: thread-per-d, h[16] in registers ----------------
__global__ __launch_bounds__(256) void k_scan1r(const float* __restrict__ dtf,
                                                const bf16* __restrict__ xih, const bf16* __restrict__ xil,
                                                const float* __restrict__ xdf, const float* __restrict__ A_log,
                                                float* __restrict__ P, float* __restrict__ R){
  int b = blockIdx.y, c = blockIdx.z;
  int d = blockIdx.x * 256 + threadIdx.x;
  __shared__ float sBC[CL2*32];
  int s0 = c * CL2;
  for (int i = threadIdx.x; i < CL2*32; i += 256)
    sBC[i] = xdf[((size_t)b*Sz + s0 + (i >> 5)) * 32 + (i & 31)];
  float Adn[16];
  #pragma unroll
  for (int n = 0; n < 16; ++n) Adn[n] = -__expf(A_log[d*16+n]);
  __syncthreads();
  float h[16];
  #pragma unroll
  for (int n = 0; n < 16; ++n) h[n] = 0.f;
  float sdt = 0.f;
  for (int s = 0; s < CL2; ++s) {
    size_t row = (size_t)b * Sz + s0 + s;
    float dtv = dtf[row * NDH + d];
    float xiv = rc(xih, xil, row * DIz + d);
    float kb = dtv * xiv;
    const float* bc = &sBC[s*32];
    sdt += dtv;
    #pragma unroll
    for (int n = 0; n < 16; ++n) {
      float da = __expf(dtv * Adn[n]);
      h[n] = da * h[n] + kb * bc[n];
    }
  }
  size_t idx = (((size_t)c * Bz + b) * NDH + d) * 16;
  #pragma unroll
  for (int n = 0; n < 16; ++n) { P[idx+n] = __expf(sdt * Adn[n]); R[idx+n] = h[n]; }
}
__global__ __launch_bounds__(256) void k_scan2(const float* __restrict__ P, const float* __restrict__ R,
                                               float* __restrict__ Hin){
  int i = blockIdx.x * 256 + threadIdx.x;
  float h = 0.f;
  #pragma unroll 4
  for (int c = 0; c < NCH2; ++c) {
    size_t idx = (size_t)c * (Bz * NDH * 16) + i;
    Hin[idx] = h;
    h = P[idx] * h + R[idx];
  }
}
__global__ __launch_bounds__(256) void k_scan3r(const float* __restrict__ dtf,
                                                const bf16* __restrict__ xih, const bf16* __restrict__ xil,
                                                const float* __restrict__ xdf, const float* __restrict__ resf,
                                                const float* __restrict__ A_log, const float* __restrict__ Dsk,
                                                const float* __restrict__ Hin,
                                                bf16* __restrict__ yh, bf16* __restrict__ yl){
  int b = blockIdx.y, c = blockIdx.z;
  int d = blockIdx.x * 256 + threadIdx.x;
  __shared__ float sBC[CL2*32];
  int s0 = c * CL2;
  for (int i = threadIdx.x; i < CL2*32; i += 256)
    sBC[i] = xdf[((size_t)b*Sz + s0 + (i >> 5)) * 32 + (i & 31)];
  float Adn[16];
  #pragma unroll
  for (int n = 0; n < 16; ++n) Adn[n] = -__expf(A_log[d*16+n]);
  float Dv = Dsk[d];
  __syncthreads();
  float h[16];
  size_t hidx = (((size_t)c * Bz + b) * NDH + d) * 16;
  #pragma unroll
  for (int n = 0; n < 16; ++n) h[n] = Hin[hidx+n];
  for (int s = 0; s < CL2; ++s) {
    size_t row = (size_t)b * Sz + s0 + s;
    float dtv = dtf[row * NDH + d];
    float xiv = rc(xih, xil, row * DIz + d);
    float kb = dtv * xiv;
    const float* bc = &sBC[s*32];
    float acc = 0.f;
    #pragma unroll
    for (int n = 0; n < 16; ++n) {
      float da = __expf(dtv * Adn[n]);
      h[n] = da * h[n] + kb * bc[n];
      acc = fmaf(h[n], bc[16+n], acc);
    }
    float resv = resf[row * DIz + d];
    float yv = (acc + xiv * Dv) * (resv / (1.f + __expf(-resv)));
    split2(yv, yh[row * NDH + d], yl[row * NDH + d]);
  }
}

// ---------------- MoE gate: 4 tokens/block, NO atomics ----------------
__global__ __launch_bounds__(256) void k_gate(const float* __restrict__ m, const float* __restrict__ nw,
                                              const float* __restrict__ gw, const float* __restrict__ gb,
                                              int* __restrict__ topi, float* __restrict__ topw){
  int t = blockIdx.x * 4 + (threadIdx.x >> 6);
  int lane = threadIdx.x & 63;
  const float* xr = m + (size_t)t * Dz;
  float xv[16];
  float ss = 0.f;
  #pragma unroll
  for (int j = 0; j < 16; ++j) { xv[j] = xr[lane + j * 64]; ss += xv[j] * xv[j]; }
  #pragma unroll
  for (int o = 32; o; o >>= 1) ss += __shfl_xor(ss, o);
  float sc = rsqrtf(ss * (1.f / Dz) + 1e-6f);
  #pragma unroll
  for (int j = 0; j < 16; ++j) xv[j] *= sc * nw[lane + j * 64];
  float acc[8] = {0.f,0.f,0.f,0.f,0.f,0.f,0.f,0.f};
  #pragma unroll
  for (int j = 0; j < 16; ++j) {
    #pragma unroll
    for (int e = 0; e < 8; ++e) acc[e] += xv[j] * gw[e * Dz + lane + j * 64];
  }
  #pragma unroll
  for (int e = 0; e < 8; ++e) {
    float v = acc[e];
    #pragma unroll
    for (int o = 32; o; o >>= 1) v += __shfl_xor(v, o);
    acc[e] = v;
  }
  if (lane == 0) {
    float mx = acc[0];
    #pragma unroll
    for (int e = 1; e < 8; ++e) mx = fmaxf(mx, acc[e]);
    float scr[8]; float sum = 0.f;
    #pragma unroll
    for (int e = 0; e < 8; ++e) { scr[e] = expf(acc[e] - mx); sum += scr[e]; }
    float inv = 1.f / sum;
    #pragma unroll
    for (int e = 0; e < 8; ++e) scr[e] *= inv;
    int i0 = 0; float b0 = -1e30f;
    #pragma unroll
    for (int e = 0; e < 8; ++e) { float kv = scr[e] + gb[e]; if (kv > b0) { b0 = kv; i0 = e; } }
    int i1 = -1; float b1 = -1e30f;
    #pragma unroll
    for (int e = 0; e < 8; ++e) { if (e == i0) continue; float kv = scr[e] + gb[e]; if (kv > b1) { b1 = kv; i1 = e; } }
    float w0 = scr[i0], w1 = scr[i1];
    float wn = 1.f / (w0 + w1 + 1e-9f);
    topi[t*2] = i0; topi[t*2+1] = i1;
    topw[t*2] = w0 * wn; topw[t*2+1] = w1 * wn;
  }
}

// ---------------- expert count: LDS histogram, 8 global atomics per block ----------------
__global__ __launch_bounds__(256) void k_count(const int* __restrict__ topi, int* __restrict__ counts){
  __shared__ int cnt[NE];
  int tid = threadIdx.x;
  if (tid < NE) cnt[tid] = 0;
  __syncthreads();
  int i = blockIdx.x * 256 + tid;
  atomicAdd(&cnt[topi[i]], 1);
  __syncthreads();
  if (tid < NE) atomicAdd(&counts[tid], cnt[tid]);
}

__global__ void k_offs(const int* __restrict__ counts, int* __restrict__ offs, int* __restrict__ fill){
  if (threadIdx.x == 0) {
    int o = 0;
    for (int e = 0; e < 8; ++e) { offs[e] = o; o += ((counts[e] + 127) & ~127); }
    offs[8] = o;
  }
  if (threadIdx.x < 8) fill[threadIdx.x] = 0;
}

// ---------------- scatter: per-block LDS positions + 8 reservation atomics ----------------
__global__ __launch_bounds__(256) void k_scatter(const int* __restrict__ topi, const float* __restrict__ topw,
                                                 const int* __restrict__ offs, int* __restrict__ fill,
                                                 int* __restrict__ toks, float* __restrict__ wslot,
                                                 int* __restrict__ slot_of){
  __shared__ int cnt[NE], basee[NE];
  int tid = threadIdx.x;
  if (tid < NE) cnt[tid] = 0;
  __syncthreads();
  int i = blockIdx.x * 256 + tid;
  int e = topi[i];
  int pos = atomicAdd(&cnt[e], 1);
  __syncthreads();
  if (tid < NE) basee[tid] = atomicAdd(&fill[tid], cnt[tid]);
  __syncthreads();
  int slot = offs[e] + basee[e] + pos;
  toks[slot] = i >> 1;
  wslot[slot] = topw[i];
  slot_of[i] = slot;
}

// ---------------- final combine: out = m + down0 + down1 ----------------
__global__ __launch_bounds__(256) void k_combine(const float* __restrict__ m,
                                                 const bf16* __restrict__ Hd, const int* __restrict__ slot_of,
                                                 float* __restrict__ out){
  int t = blockIdx.x;
  int ci = threadIdx.x * 4;
  int s0 = slot_of[t*2], s1 = slot_of[t*2+1];
  size_t base = (size_t)t * Dz + ci;
  float4 mv = *(const float4*)(m + base);
  ushort4 h0 = *(const ushort4*)((const unsigned short*)Hd + (size_t)s0 * Dz + ci);
  ushort4 h1 = *(const ushort4*)((const unsigned short*)Hd + (size_t)s1 * Dz + ci);
  out[base+0] = mv.x + us2f(h0.x) + us2f(h1.x);
  out[base+1] = mv.y + us2f(h0.y) + us2f(h1.y);
  out[base+2] = mv.z + us2f(h0.z) + us2f(h1.z);
  out[base+3] = mv.w + us2f(h0.w) + us2f(h1.w);
}

extern "C" void kernel_launch(void* const* d_in, const int* in_sizes, int n_in,
                              void* d_out, int out_size, void* d_ws, size_t ws_size,
                              hipStream_t stream) {
  (void)in_sizes; (void)n_in; (void)out_size;
  const float* x         = (const float*)d_in[0];
  const float* norm_w    = (const float*)d_in[1];
  const float* in_proj   = (const float*)d_in[2];
  const float* conv_w    = (const float*)d_in[3];
  const float* conv_b    = (const float*)d_in[4];
  const float* x_proj    = (const float*)d_in[5];
  const float* dt_proj   = (const float*)d_in[6];
  const float* dt_proj_b = (const float*)d_in[7];
  const float* A_log     = (const float*)d_in[8];
  const float* D_skip    = (const float*)d_in[9];
  const float* out_proj  = (const float*)d_in[10];
  const float* gate_w    = (const float*)d_in[11];
  const float* gate_b    = (const float*)d_in[12];
  const float* w_gate    = (const float*)d_in[13];
  const float* w_up      = (const float*)d_in[14];
  const float* w_down    = (const float*)d_in[15];
  const float* ws_gate   = (const float*)d_in[16];
  const float* ws_up     = (const float*)d_in[17];
  const float* ws_down   = (const float*)d_in[18];
  float* out = (float*)d_out;

  const size_t MB = 1024 * 1024;
  const size_t NEED = 253 * MB;
  if (ws_size < NEED) {
    k_fill<<<dim3(1), dim3(256), 0, stream>>>(out, (float)(ws_size / MB));
    fprintf(stderr, "kernel_launch: ws_size=%zu < needed=%zu\n", ws_size, NEED);
    return;
  }
  char* P = (char*)d_ws;
  // ---- phase A layout ----
  float* res_f = (float*)(P + 0*MB);
  bf16*  xi_h  = (bf16*)(P + 64*MB);
  bf16*  xi_l  = (bf16*)(P + 96*MB);
  bf16*  xd_h  = (bf16*)(P + 128*MB);
  bf16*  xd_l  = (bf16*)(P + 130*MB);
  float* xdf   = (float*)(P + 132*MB);
  bf16*  xph   = (bf16*)(P + 133*MB);
  bf16*  xpl   = (bf16*)(P + 133*MB + 512*1024);
  bf16*  dph   = (bf16*)(P + 134*MB);
  bf16*  dpl   = (bf16*)(P + 134*MB + 256*1024);
  bf16*  oph   = (bf16*)(P + 135*MB);
  bf16*  opl   = (bf16*)(P + 139*MB);
  float* dtf   = (float*)(P + 144*MB);
  float* scanH = (float*)(P + 176*MB);
  bf16*  y_h   = (bf16*)(P + 188*MB);
  float* scanP = (float*)(P + 192*MB);
  float* scanR = (float*)(P + 200*MB);
  bf16*  y_l   = (bf16*)(P + 204*MB);
  float* mbuf  = (float*)(P + 220*MB);
  // transients:
  bf16*  nrm_h = (bf16*)(P + 144*MB);
  bf16*  nrm_l = (bf16*)(P + 160*MB);
  bf16*  iph   = (bf16*)(P + 176*MB);
  bf16*  ipl   = (bf16*)(P + 184*MB);
  float* xzi_f = (float*)(P + 192*MB);
  // ---- phase B (MoE) overlay ----
  bf16* n2b   = (bf16*)(P + 0*MB);
  bf16* wgh   = (bf16*)(P + 16*MB);
  bf16* wuh   = (bf16*)(P + 32*MB);
  bf16* wdh   = (bf16*)(P + 48*MB);
  bf16* wsg   = (bf16*)(P + 64*MB);
  bf16* wsu   = (bf16*)(P + 68*MB);
  bf16* wsd   = (bf16*)(P + 72*MB);
  bf16* Hbuf  = (bf16*)(P + 76*MB);    // G (routed) then H after silumul; 34MB
  bf16* Hd    = (bf16*)(P + 110*MB);   // 34MB
  bf16* Sh    = (bf16*)(P + 144*MB);   // G (shared) then H; 32MB
  bf16* Utmp  = (bf16*)(P + 176*MB);   // 34MB (over dead scan/y region)
  char* Rt    = P + 252*MB;
  int*   counts  = (int*)(Rt);
  int*   offsb   = (int*)(Rt + 64);
  int*   fill    = (int*)(Rt + 128);
  int*   topi    = (int*)(Rt + 1024);
  float* topw    = (float*)(Rt + 1024 + 65536);
  int*   toks    = (int*)(Rt + 1024 + 2*65536);
  float* wslot   = (float*)(Rt + 1024 + 2*65536 + 69632);
  int*   slot_of = (int*)(Rt + 1024 + 2*65536 + 2*69632);

  // fused mamba weight splits + x_proj pad
  k_split3<<<dim3(6272), dim3(256), 0, stream>>>(in_proj, iph, ipl, out_proj, oph, opl, dt_proj, dph, dpl);
  k_split_pad<<<dim3(256), dim3(256), 0, stream>>>(x_proj, xph, xpl);

  // 1. rmsnorm(x) -> normed hi/lo
  k_rmsnorm<true><<<dim3(Tz), dim3(256), 0, stream>>>(x, norm_w, nrm_h, nrm_l);
  // 2. in_proj: dual f32 store -> xzi_f / res_f (single merged dispatch, best measured)
  k_inproj<<<dim3(Tz/128, 4096/128), dim3(256), 0, stream>>>(nrm_h, nrm_l, iph, ipl, xzi_f, res_f);
  // 3. causal conv + silu -> xi hi/lo
  k_conv4<<<dim3(DIz/256, Tz/4), dim3(256), 0, stream>>>(xzi_f, conv_w, conv_b, xi_h, xi_l);
  // 4. x_proj -> xd hi/lo + xdf f32 (B|C)
  k_xproj<<<dim3(Tz/128, 1), dim3(256), 0, stream>>>(xi_h, xi_l, xph, xpl, xd_h, xd_l, xdf);

  // 5-7. per d-half: dt_proj -> scan -> out_proj partial
  for (int h = 0; h < 2; ++h) {
    int d0 = h * NDH;
    k_dtproj<<<dim3(Tz/128, NDH/128), dim3(256), 0, stream>>>(
        xd_h, xd_l, dph + (size_t)d0*DTRz, dpl + (size_t)d0*DTRz, dtf, dt_proj_b + d0);
    k_scan1r<<<dim3(NDH/256, Bz, NCH2), dim3(256), 0, stream>>>(
        dtf, xi_h + d0, xi_l + d0, xdf, A_log + (size_t)d0*DSz, scanP, scanR);
    k_scan2<<<dim3(Bz*NDH*DSz/256), dim3(256), 0, stream>>>(scanP, scanR, scanH);
    k_scan3r<<<dim3(NDH/256, Bz, NCH2), dim3(256), 0, stream>>>(
        dtf, xi_h + d0, xi_l + d0, xdf, res_f + d0, A_log + (size_t)d0*DSz,
        D_skip + d0, scanH, y_h, y_l);
    if (h == 0)
      k_outproj<3><<<dim3(Tz/128, Dz/128), dim3(256), 0, stream>>>(
          y_h, y_l, oph + d0, opl + d0, mbuf, x);
    else
      k_outproj<4><<<dim3(Tz/128, Dz/128), dim3(256), 0, stream>>>(
          y_h, y_l, oph + d0, opl + d0, mbuf, nullptr);
  }

  // MoE weight conversion
  k_f2bf6<<<dim3(30720), dim3(256), 0, stream>>>(
      w_gate, wgh, w_up, wuh, w_down, wdh, ws_gate, wsg, ws_up, wsu, ws_down, wsd);
  // 8. rmsnorm(m) -> n2 bf16
  k_rmsnorm<false><<<dim3(Tz), dim3(256), 0, stream>>>(mbuf, norm_w, n2b, nullptr);
  // 9. gate (no atomics) + count + routing
  k_gate<<<dim3(Tz/4), dim3(256), 0, stream>>>(mbuf, norm_w, gate_w, gate_b, topi, topw);
  k_zero_counts<<<dim3(1), dim3(64), 0, stream>>>(counts);
  k_count<<<dim3(Tz*2/256), dim3(256), 0, stream>>>(topi, counts);
  k_offs<<<dim3(1), dim3(64), 0, stream>>>(counts, offsb, fill);
  k_scatter<<<dim3(Tz*2/256), dim3(256), 0, stream>>>(topi, topw, offsb, fill, toks, wslot, slot_of);
  // 10. routed experts: merged gate|up GEMM, silumul, down
  k_moe_glu_r<<<dim3(SLOTCAP/128, 16), dim3(256), 0, stream>>>(
      n2b, wgh, wuh, Hbuf, Utmp, offsb, toks, counts);
  k_silumul<<<dim3((unsigned)((size_t)SLOTCAP*Fz/2048)), dim3(256), 0, stream>>>(Hbuf, Utmp);
  k_down_routed<<<dim3(SLOTCAP/128, Dz/128), dim3(256), 0, stream>>>(
      Hbuf, wdh, Hd, wslot, offsb, counts);
  // 11. shared expert: merged gate|up GEMM, silumul
  k_moe_glu_s<<<dim3(Tz/128, 32), dim3(256), 0, stream>>>(n2b, wsg, wsu, Sh, Utmp);
  k_silumul<<<dim3((unsigned)((size_t)Tz*FSz/2048)), dim3(256), 0, stream>>>(Sh, Utmp);
  // 12. combine -> out = m + routed
  k_combine<<<dim3(Tz), dim3(256), 0, stream>>>(mbuf, Hd, slot_of, out);
  // 13. shared down: out += Sh @ ws_down^T
  k_down_shared<<<dim3(Tz/128, Dz/128), dim3(256), 0, stream>>>(Sh, wsd, out);
}